// Round 7
// baseline (370.443 us; speedup 1.0000x reference)
//
#include <hip/hip_runtime.h>
#include <math.h>

typedef __attribute__((ext_vector_type(8))) short short8;      // 8 bf16 (4 VGPRs) MFMA operand
typedef __attribute__((ext_vector_type(4))) float floatx4;     // 16x16 MFMA accumulator
typedef __attribute__((ext_vector_type(16))) float floatx16;   // 32x32 MFMA accumulator
typedef __attribute__((ext_vector_type(8))) unsigned short ushort8v;
typedef __attribute__((ext_vector_type(4))) unsigned short ushort4v;

#define HW 4096
#define CCH 512
#define NB 4
#define NH 4
#define HD 128

__device__ __forceinline__ unsigned short f2bf(float f) {
    union { float f; unsigned int u; } c; c.f = f;
    unsigned int u = c.u;
    u += 0x7FFFu + ((u >> 16) & 1u);   // round-to-nearest-even
    return (unsigned short)(u >> 16);
}

// async global->LDS DMA, 16B per lane. LDS dest = wave-uniform base + lane*16 (linear);
// swizzled layouts are achieved by permuting the per-lane GLOBAL source address.
__device__ __forceinline__ void gload_lds16(const unsigned short* g, unsigned short* l) {
    __builtin_amdgcn_global_load_lds(
        (const __attribute__((address_space(1))) unsigned int*)g,
        (__attribute__((address_space(3))) unsigned int*)l, 16, 0, 0);
}

__device__ __forceinline__ float sum16(const floatx16& s) {
    return ((((s[0] + s[1]) + (s[2] + s[3])) + ((s[4] + s[5]) + (s[6] + s[7])))
          + (((s[8] + s[9]) + (s[10] + s[11])) + ((s[12] + s[13]) + (s[14] + s[15]))));
}

// ---------------- weights fp32 -> bf16 ----------------
__global__ void conv_w(const float* __restrict__ w0, const float* __restrict__ w1,
                       const float* __restrict__ w2, const float* __restrict__ w3,
                       unsigned short* __restrict__ dst) {
    const float* src = blockIdx.y == 0 ? w0 : blockIdx.y == 1 ? w1 : blockIdx.y == 2 ? w2 : w3;
    unsigned short* d = dst + (size_t)blockIdx.y * 262144;
    int i = blockIdx.x * 256 + threadIdx.x;          // float4 index, 65536 total
    float4 v = ((const float4*)src)[i];
    ushort4v o;
    o[0] = f2bf(v.x); o[1] = f2bf(v.y); o[2] = f2bf(v.z); o[3] = f2bf(v.w);
    ((ushort4v*)d)[i] = o;
}

// ---------------- GroupNorm stats: one block per (b, group) ----------------
__global__ void gn_stats(const float* __restrict__ x, float* __restrict__ stats) {
    int bg = blockIdx.x;                 // 0..127
    int b = bg >> 5, g = bg & 31;
    const float4* p = (const float4*)(x + ((size_t)b * CCH + g * 16) * HW);  // 16 ch * 4096 contiguous
    float s = 0.f, ss = 0.f;
    for (int i = threadIdx.x; i < 16384; i += 256) {
        float4 v = p[i];
        s  += v.x + v.y + v.z + v.w;
        ss += v.x * v.x + v.y * v.y + v.z * v.z + v.w * v.w;
    }
    #pragma unroll
    for (int off = 32; off > 0; off >>= 1) {
        s  += __shfl_down(s, off, 64);
        ss += __shfl_down(ss, off, 64);
    }
    __shared__ float sm[4], sm2[4];
    int wid = threadIdx.x >> 6;
    if ((threadIdx.x & 63) == 0) { sm[wid] = s; sm2[wid] = ss; }
    __syncthreads();
    if (threadIdx.x == 0) {
        float ts = sm[0] + sm[1] + sm[2] + sm[3];
        float tss = sm2[0] + sm2[1] + sm2[2] + sm2[3];
        float mean = ts * (1.f / 65536.f);
        float var = tss * (1.f / 65536.f) - mean * mean;
        stats[bg * 2] = mean;
        stats[bg * 2 + 1] = rsqrtf(var + 1e-5f);
    }
}

// ---------------- normalize + transpose -> XT[b, s, c] bf16 ----------------
__global__ void gn_apply(const float* __restrict__ x, const float* __restrict__ gnw,
                         const float* __restrict__ gnb, const float* __restrict__ stats,
                         unsigned short* __restrict__ xt) {
    int s = blockIdx.x * 256 + threadIdx.x;   // 0..4095
    int g = blockIdx.y, b = blockIdx.z;
    float mean = stats[(b * 32 + g) * 2];
    float rstd = stats[(b * 32 + g) * 2 + 1];
    const float* xb = x + ((size_t)b * CCH + g * 16) * HW + s;
    unsigned short outv[16];
    #pragma unroll
    for (int cl = 0; cl < 16; cl++) {
        int c = g * 16 + cl;
        float v = xb[(size_t)cl * HW];                       // lanes->consecutive s: coalesced
        v = (v - mean) * rstd * gnw[c] + gnb[c];
        outv[cl] = f2bf(v);
    }
    unsigned short* dst = xt + ((size_t)b * HW + s) * CCH + g * 16;   // 32B contiguous per thread
    *(ushort8v*)dst       = *(ushort8v*)&outv[0];
    *(ushort8v*)(dst + 8) = *(ushort8v*)&outv[8];
}

// ---------------- NT GEMM: C[m,n] = sum_k A[m,k] B[n,k], K=512 ----------------
// MODE 0: C bf16 [m,n], bias per-col n, *scale      (single projection)
// MODE 1: C fp32 [m,n], bias per-row m, + residual  (output projection + residual)
// MODE 2: C bf16 [m,n], bias per-row m              (V projection, stored transposed)
// MODE 3: dual-launch over z: z=0 -> Q (bias, scale) in row-major [m][n];
//         z=1 -> K (resid-as-bias) written in MFMA-FRAGMENT-PACKED layout:
//         Kf[(b*NH+h)*HW*HD + ((s>>5)*8 + (d>>4))*512 + ((d>>3)&1)*256 + (s&31)*8 + (d&7)]
//         so each attn QK A-fragment is one fully-coalesced 1KB global_load_dwordx4.
// Reg-prefetch + LDS double-buffer: ONE barrier per K-step, global latency hidden under MFMA.
#define LDP 72   // padded leading dim (ushorts): 72*2=144B, 16B-aligned, 36 dwords == 4 mod 32 banks
template <int MODE>
__global__ __launch_bounds__(256, 2) void gemm_nt(
    const unsigned short* __restrict__ A, long long aStride,
    const unsigned short* __restrict__ Bm, long long bStride,
    const float* __restrict__ bias, float scale,
    const float* __restrict__ resid, long long rStride,
    void* __restrict__ Cp, long long cStride, int ldc) {
    __shared__ unsigned short lA[2][128 * LDP];
    __shared__ unsigned short lB[2][128 * LDP];
    const int tid = threadIdx.x;
    const int lane = tid & 63;
    const int wid = tid >> 6;
    const int z = blockIdx.z;
    const unsigned short* Ab = A + (size_t)z * aStride + (size_t)blockIdx.x * 128 * 512;
    const unsigned short* Bb = Bm + (size_t)z * bStride + (size_t)blockIdx.y * 128 * 512;

    floatx4 acc[4][4];
    #pragma unroll
    for (int i = 0; i < 4; i++)
        #pragma unroll
        for (int j = 0; j < 4; j++) acc[i][j] = (floatx4)0.f;

    const int wm = (wid >> 1) * 64;
    const int wn = (wid & 1) * 64;
    const int l15 = lane & 15;
    const int l4 = lane >> 4;
    const int srow = tid >> 3;            // 0..31 base row block (idx>>3 for i=0)
    const int skc  = (tid & 7) * 8;       // k-chunk within 64

    ushort8v ar[4], br[4];
    // prologue: tile 0 -> regs -> LDS buf 0
    #pragma unroll
    for (int i = 0; i < 4; i++) {
        int row = srow + i * 32;
        ar[i] = *(const ushort8v*)&Ab[(size_t)row * 512 + skc];
        br[i] = *(const ushort8v*)&Bb[(size_t)row * 512 + skc];
    }
    #pragma unroll
    for (int i = 0; i < 4; i++) {
        int row = srow + i * 32;
        *(ushort8v*)&lA[0][row * LDP + skc] = ar[i];
        *(ushort8v*)&lB[0][row * LDP + skc] = br[i];
    }
    __syncthreads();

    int cur = 0;
    #pragma unroll 1
    for (int t = 0; t < 8; t++) {
        // prefetch next K-tile into regs (latency hides under the MFMAs below)
        if (t < 7) {
            int k0 = (t + 1) * 64;
            #pragma unroll
            for (int i = 0; i < 4; i++) {
                int row = srow + i * 32;
                ar[i] = *(const ushort8v*)&Ab[(size_t)row * 512 + k0 + skc];
                br[i] = *(const ushort8v*)&Bb[(size_t)row * 512 + k0 + skc];
            }
        }
        #pragma unroll
        for (int kk = 0; kk < 2; kk++) {
            short8 af[4], bf[4];
            #pragma unroll
            for (int i = 0; i < 4; i++)
                af[i] = *(const short8*)&lA[cur][(wm + i * 16 + l15) * LDP + kk * 32 + l4 * 8];
            #pragma unroll
            for (int j = 0; j < 4; j++)
                bf[j] = *(const short8*)&lB[cur][(wn + j * 16 + l15) * LDP + kk * 32 + l4 * 8];
            #pragma unroll
            for (int i = 0; i < 4; i++)
                #pragma unroll
                for (int j = 0; j < 4; j++)
                    acc[i][j] = __builtin_amdgcn_mfma_f32_16x16x32_bf16(af[i], bf[j], acc[i][j], 0, 0, 0);
        }
        if (t < 7) {
            int nxt = cur ^ 1;
            #pragma unroll
            for (int i = 0; i < 4; i++) {
                int row = srow + i * 32;
                *(ushort8v*)&lA[nxt][row * LDP + skc] = ar[i];
                *(ushort8v*)&lB[nxt][row * LDP + skc] = br[i];
            }
            __syncthreads();
            cur = nxt;
        }
    }

    long long m0 = (long long)blockIdx.x * 128 + wm;
    long long n0 = (long long)blockIdx.y * 128 + wn;
    if (MODE == 3 && blockIdx.z == 1) {
        // K projection -> fragment-packed Kf layout (see header comment)
        unsigned short* C = (unsigned short*)Cp + (size_t)cStride;   // z==1
        const int hh = blockIdx.y;                                   // head (N-block == head)
        #pragma unroll
        for (int i = 0; i < 4; i++)
            #pragma unroll
            for (int j = 0; j < 4; j++) {
                long long col = n0 + j * 16 + l15;
                float bv = resid[col];                               // bk
                int d = (int)(col - (long long)hh * 128);            // 0..127 within head
                size_t dpart = (size_t)((d >> 4) * 2 + ((d >> 3) & 1)) * 256 + (size_t)(d & 7);
                #pragma unroll
                for (int r = 0; r < 4; r++) {
                    long long row = m0 + i * 16 + l4 * 4 + r;        // = b*4096 + s
                    int bb = (int)(row >> 12), s = (int)(row & 4095);
                    size_t addr = ((size_t)(bb * NH + hh)) * ((size_t)HW * HD)
                                + (size_t)(s >> 5) * 4096 + dpart + (size_t)(s & 31) * 8;
                    C[addr] = f2bf(acc[i][j][r] + bv);
                }
            }
    } else if (MODE == 0 || MODE == 3) {
        unsigned short* C = (unsigned short*)Cp + (size_t)z * cStride;
        #pragma unroll
        for (int i = 0; i < 4; i++)
            #pragma unroll
            for (int j = 0; j < 4; j++) {
                long long col = n0 + j * 16 + l15;
                float bv = bias[col];
                #pragma unroll
                for (int r = 0; r < 4; r++) {
                    long long row = m0 + i * 16 + l4 * 4 + r;    // D: row=(lane>>4)*4+reg, col=lane&15
                    C[row * ldc + col] = f2bf((acc[i][j][r] + bv) * scale);
                }
            }
    } else if (MODE == 1) {
        float* C = (float*)Cp + (size_t)z * cStride;
        const float* R = resid + (size_t)z * rStride;
        #pragma unroll
        for (int i = 0; i < 4; i++)
            #pragma unroll
            for (int j = 0; j < 4; j++)
                #pragma unroll
                for (int r = 0; r < 4; r++) {
                    long long row = m0 + i * 16 + l4 * 4 + r;    // row = output channel o
                    long long col = n0 + j * 16 + l15;           // col = spatial s (coalesced)
                    C[row * ldc + col] = acc[i][j][r] + bias[row] + R[row * ldc + col];
                }
    } else {
        unsigned short* C = (unsigned short*)Cp + (size_t)z * cStride;
        #pragma unroll
        for (int i = 0; i < 4; i++)
            #pragma unroll
            for (int j = 0; j < 4; j++)
                #pragma unroll
                for (int r = 0; r < 4; r++) {
                    long long row = m0 + i * 16 + l4 * 4 + r;    // row = channel c (V^T layout)
                    long long col = n0 + j * 16 + l15;           // col = spatial s
                    C[row * ldc + col] = f2bf(acc[i][j][r] + bias[row]);
                }
    }
}

// ---------------- flash attention (no-max, 32x32 MFMA, K-from-global, V-DMA) ----------------
// One block per (q-tile 128, head, batch). Q pre-scaled by log2(e)/sqrt(hd) -> p = exp2(S).
//
// K path: fragment-packed Kf in global (written by gemm MODE3 z=1). Each QK A-fragment is ONE
//   coalesced 1KB global_load_dwordx4 (per-lane addr = chunk + lane*8); the 4 waves of a block
//   read the same 16KB chunk -> L1 serves repeats. kf regs loaded one iteration ahead; QK is
//   then ALL-REGISTER. This removes K from LDS entirely: LDS read traffic halves (the LDS port
//   was co-dominant with MFMA at ~2500 cyc/kt/CU), K moves to the parallel vmem pipe.
// V path: global_load_lds DMA, double-buffered, XOR-swizzled source + swizzled b128 read.
// lsum: VALU add-tree over exp2 outputs (frees 4 MFMA/wave/kt); finalize via permlane32_swap,
//   epilogue redistributes with __shfl.
// Schedule per kt (ONE barrier): [V-DMA(kt+1)] [QK(kt) all-reg] [kf loads(kt+1)] [pack+lsum]
//   [PV(kt) from lvCur] [barrier; swap].
// __launch_bounds__(256,2): persistent regs ~ acc_o 64 + kf 64 + qf 32 + sa 32 + misc -> ~215.
// WRITE_SIZE must stay 16384 (spill tripwire; R6's lambda structure spilled at 22528).
__global__ __launch_bounds__(256, 2) void attn_kern(
    const unsigned short* __restrict__ Qb, const unsigned short* __restrict__ Kf,
    const unsigned short* __restrict__ Vt, unsigned short* __restrict__ Ob) {
    __shared__ __align__(16) unsigned short lv0[8192], lv1[8192];   // V tiles [128 d][64 t] (swizzled slots)
    const int tid = threadIdx.x;
    const int lane = tid & 63;
    const int w = tid >> 6;
    const int l31 = lane & 31;
    const int l1 = lane >> 5;
    const int q0 = blockIdx.x * 128;
    const int h = blockIdx.y, b = blockIdx.z;
    const size_t headOff = (size_t)h * HD;
    const size_t batchRow = (size_t)b * HW;
    const unsigned short* VtB = Vt + ((size_t)b * CCH + headOff) * HW;            // [d][s]
    const unsigned short* KfB = Kf + (size_t)(b * NH + h) * ((size_t)HW * HD);    // fragment-packed

    // V DMA source indices (ushort units), XOR-swizzled per-lane global source
    size_t vSrc[4];
    #pragma unroll
    for (int n = 0; n < 4; n++) {
        int d = w * 32 + n * 8 + (lane >> 3);
        int jv = (lane & 7) ^ (d & 7);
        vSrc[n] = (size_t)d * HW + jv * 8;
    }
    const int ldsOff = w * 4 * 512;   // wave-uniform LDS chunk base (ushorts)
    const int sv0 = l31 & 7;          // V read-side swizzle

    // Q fragments in registers: wave w owns q-rows [w*32, w*32+32); B[n=q=l31][k=d=kd*16+l1*8+e]
    short8 qf[8];
    #pragma unroll
    for (int kd = 0; kd < 8; kd++)
        qf[kd] = *(const short8*)&Qb[(batchRow + q0 + w * 32 + l31) * 512
                                     + headOff + kd * 16 + l1 * 8];

    floatx16 acc_o[4];   // O[q][d]: col d = dj*32+l31, row q = (reg&3)+8*(reg>>2)+4*l1
    #pragma unroll
    for (int dj = 0; dj < 4; dj++) acc_o[dj] = (floatx16)0.f;
    float lsum_part = 0.f;

    // prologue: DMA V(0)->lv0; load kf(0) fragments (coalesced 1KB each)
    #pragma unroll
    for (int n = 0; n < 4; n++) gload_lds16(&VtB[vSrc[n]], lv0 + ldsOff + n * 512);
    short8 kf0[8], kf1[8];
    {
        const unsigned short* kb = KfB + lane * 8;
        #pragma unroll
        for (int kd = 0; kd < 8; kd++) {
            kf0[kd] = *(const short8*)(kb + kd * 512);
            kf1[kd] = *(const short8*)(kb + 4096 + kd * 512);
        }
    }
    __syncthreads();   // publish lv0 (also drains kf loads)

    unsigned short* lvCur = lv0;  unsigned short* lvNxt = lv1;

    #pragma unroll 1
    for (int kt = 0; kt < 64; kt++) {
        // issue V DMA for kt+1 (dest buffer consumed before previous barrier)
        if (kt < 63) {
            size_t tv = (size_t)(kt + 1) * 64;
            #pragma unroll
            for (int n = 0; n < 4; n++) gload_lds16(&VtB[vSrc[n] + tv], lvNxt + ldsOff + n * 512);
        }

        // ---- QK(kt): all-register ----
        floatx16 sa0 = (floatx16)0.f, sa1 = (floatx16)0.f;
        __builtin_amdgcn_s_setprio(1);
        #pragma unroll
        for (int kd = 0; kd < 8; kd++) {
            sa0 = __builtin_amdgcn_mfma_f32_32x32x16_bf16(kf0[kd], qf[kd], sa0, 0, 0, 0);
            sa1 = __builtin_amdgcn_mfma_f32_32x32x16_bf16(kf1[kd], qf[kd], sa1, 0, 0, 0);
        }
        __builtin_amdgcn_s_setprio(0);

        // ---- load kf(kt+1): kf regs free after the QK above; land by next iter's QK ----
        if (kt < 63) {
            const unsigned short* kb = KfB + (size_t)(kt + 1) * 8192 + lane * 8;
            #pragma unroll
            for (int kd = 0; kd < 8; kd++) {
                kf0[kd] = *(const short8*)(kb + kd * 512);
                kf1[kd] = *(const short8*)(kb + 4096 + kd * 512);
            }
        }

        // ---- pack(kt): exp2, lsum partial, cvt_pk + permlane32_swap -> paf ----
        short8 paf[4];
        #pragma unroll
        for (int r = 0; r < 16; r++) sa0[r] = __builtin_amdgcn_exp2f(sa0[r]);
        #pragma unroll
        for (int r = 0; r < 16; r++) sa1[r] = __builtin_amdgcn_exp2f(sa1[r]);
        lsum_part += sum16(sa0) + sum16(sa1);
        #pragma unroll
        for (int tb = 0; tb < 2; tb++) {
            const floatx16& sa = tb ? sa1 : sa0;
            unsigned int wv[4][2];
            #pragma unroll
            for (int g = 0; g < 4; g++) {
                asm("v_cvt_pk_bf16_f32 %0, %1, %2" : "=v"(wv[g][0])
                    : "v"(sa[4 * g + 0]), "v"(sa[4 * g + 1]));
                asm("v_cvt_pk_bf16_f32 %0, %1, %2" : "=v"(wv[g][1])
                    : "v"(sa[4 * g + 2]), "v"(sa[4 * g + 3]));
            }
            #pragma unroll
            for (int hh = 0; hh < 2; hh++) {
                unsigned int a0 = wv[2 * hh][0], b0 = wv[2 * hh + 1][0];
                unsigned int a1 = wv[2 * hh][1], b1 = wv[2 * hh + 1][1];
                asm("v_permlane32_swap_b32 %0, %1" : "+v"(a0), "+v"(b0));
                asm("v_permlane32_swap_b32 %0, %1" : "+v"(a1), "+v"(b1));
                union { unsigned int u[4]; short8 s8; } f;
                f.u[0] = a0; f.u[1] = a1; f.u[2] = b0; f.u[3] = b1;
                paf[2 * tb + hh] = f.s8;
            }
        }

        // ---- PV(kt): 16 MFMA reading lvCur (conflict-managed b128) ----
        __builtin_amdgcn_s_setprio(1);
        #pragma unroll
        for (int u = 0; u < 4; u++) {
            int xv = ((u * 2 + l1) ^ sv0) * 8;
            #pragma unroll
            for (int dj = 0; dj < 4; dj++) {
                short8 vv = *(const short8*)&lvCur[dj * 2048 + l31 * 64 + xv];
                acc_o[dj] = __builtin_amdgcn_mfma_f32_32x32x16_bf16(paf[u], vv, acc_o[dj], 0, 0, 0);
            }
        }
        __builtin_amdgcn_s_setprio(0);

        if (kt < 63) {
            __syncthreads();   // drains V-DMA, publishes V(kt+1)
            unsigned short* t_ = lvCur; lvCur = lvNxt; lvNxt = t_;
        }
    }

    // lsum finalize: own-half + partner-half -> lsum[q=l31] in every lane
    float tot;
    {
        union { float f; unsigned int u; } ua, ub;
        ua.f = lsum_part; ub.f = lsum_part;
        asm("v_permlane32_swap_b32 %0, %1" : "+v"(ua.u), "+v"(ub.u));
        tot = ua.f + ub.f;
    }

    // epilogue: acc_o[dj][reg] is q-row qr = (reg&3)+8*(reg>>2)+4*l1; lsum[qr] lives in lane qr
    #pragma unroll
    for (int g = 0; g < 4; g++)
        #pragma unroll
        for (int p = 0; p < 4; p++) {
            int reg = 4 * g + p;
            int qr = p + 8 * g + 4 * l1;
            float rl = 1.f / __shfl(tot, qr, 64);
            size_t row = batchRow + q0 + w * 32 + qr;
            #pragma unroll
            for (int dj = 0; dj < 4; dj++)
                Ob[row * 512 + headOff + dj * 32 + l31] = f2bf(acc_o[dj][reg] * rl);
        }
}

extern "C" void kernel_launch(void* const* d_in, const int* in_sizes, int n_in,
                              void* d_out, int out_size, void* d_ws, size_t ws_size,
                              hipStream_t stream) {
    const float* x   = (const float*)d_in[0];
    const float* gnw = (const float*)d_in[1];
    const float* gnb = (const float*)d_in[2];
    const float* wq  = (const float*)d_in[3];
    const float* bq  = (const float*)d_in[4];
    const float* wk  = (const float*)d_in[5];
    const float* bk  = (const float*)d_in[6];
    const float* wv  = (const float*)d_in[7];
    const float* bv  = (const float*)d_in[8];
    const float* wp  = (const float*)d_in[9];
    const float* bp  = (const float*)d_in[10];
    float* out = (float*)d_out;

    const size_t NE = (size_t)NB * HW * CCH;          // 8388608 elements
    unsigned short* ws16 = (unsigned short*)d_ws;
    unsigned short* XT = ws16;                        // x_n transposed (b,s,c); reused as attn O
    unsigned short* Qb = ws16 + NE;
    unsigned short* Kb = ws16 + 2 * NE;               // K in fragment-packed layout (Kf)
    unsigned short* Vt = ws16 + 3 * NE;               // V transposed: [b][c][s]
    unsigned short* Wb = ws16 + 4 * NE;               // 4 x 262144 bf16 weights
    float* stats = (float*)(ws16 + 4 * NE + 4 * 262144);

    // fold log2(e) into the attention scale so the kernel uses exp2 directly
    const float qscale = 0.08838834764831845f * 1.4426950408889634f;

    conv_w<<<dim3(256, 4), 256, 0, stream>>>(wq, wk, wv, wp, Wb);
    gn_stats<<<128, 256, 0, stream>>>(x, stats);
    gn_apply<<<dim3(16, 32, 4), 256, 0, stream>>>(x, gnw, gnb, stats, XT);

    // Q and K projections fused: z=0 -> Q (bias bq, *qscale, row-major), z=1 -> K (bias bk,
    // fragment-packed Kf layout for the attention kernel's direct-from-global QK operands)
    gemm_nt<3><<<dim3(128, 4, 2), 256, 0, stream>>>(XT, 0, Wb, 262144, bq, qscale, bk, 0,
                                                    Qb, (long long)NE, 512);
    // V stored transposed: Vt[b][c][s] = Wv @ XT[b]^T
    gemm_nt<2><<<dim3(4, 32, 4), 256, 0, stream>>>(Wb + 2 * 262144, 0, XT, (long long)HW * 512, bv, 1.f,
                                                   nullptr, 0, Vt, (long long)CCH * HW, HW);

    unsigned short* Ob = XT;   // XT dead after QKV; reuse for attention output (b,s,c)
    attn_kern<<<dim3(32, NH, NB), 256, 0, stream>>>(Qb, Kb, Vt, Ob);

    // out[b,o,s] = sum_c wp[o,c] * Ob[b,s,c] + bp[o] + x[b,o,s]
    gemm_nt<1><<<dim3(4, 32, 4), 256, 0, stream>>>(Wb + 3 * 262144, 0, Ob, (long long)HW * 512, bp, 1.f,
                                                   x, (long long)CCH * HW, out, (long long)CCH * HW, HW);
}

// Round 8
// 336.004 us; speedup vs baseline: 1.1025x; 1.1025x over previous
//
#include <hip/hip_runtime.h>
#include <math.h>

typedef __attribute__((ext_vector_type(8))) short short8;      // 8 bf16 (4 VGPRs) MFMA operand
typedef __attribute__((ext_vector_type(4))) float floatx4;     // 16x16 MFMA accumulator
typedef __attribute__((ext_vector_type(16))) float floatx16;   // 32x32 MFMA accumulator
typedef __attribute__((ext_vector_type(8))) unsigned short ushort8v;
typedef __attribute__((ext_vector_type(4))) unsigned short ushort4v;

#define HW 4096
#define CCH 512
#define NB 4
#define NH 4
#define HD 128

__device__ __forceinline__ unsigned short f2bf(float f) {
    union { float f; unsigned int u; } c; c.f = f;
    unsigned int u = c.u;
    u += 0x7FFFu + ((u >> 16) & 1u);   // round-to-nearest-even
    return (unsigned short)(u >> 16);
}

// async global->LDS DMA, 16B per lane. LDS dest = wave-uniform base + lane*16 (linear);
// swizzled layouts are achieved by permuting the per-lane GLOBAL source address.
__device__ __forceinline__ void gload_lds16(const unsigned short* g, unsigned short* l) {
    __builtin_amdgcn_global_load_lds(
        (const __attribute__((address_space(1))) unsigned int*)g,
        (__attribute__((address_space(3))) unsigned int*)l, 16, 0, 0);
}

// ---------------- weights fp32 -> bf16 ----------------
__global__ void conv_w(const float* __restrict__ w0, const float* __restrict__ w1,
                       const float* __restrict__ w2, const float* __restrict__ w3,
                       unsigned short* __restrict__ dst) {
    const float* src = blockIdx.y == 0 ? w0 : blockIdx.y == 1 ? w1 : blockIdx.y == 2 ? w2 : w3;
    unsigned short* d = dst + (size_t)blockIdx.y * 262144;
    int i = blockIdx.x * 256 + threadIdx.x;          // float4 index, 65536 total
    float4 v = ((const float4*)src)[i];
    ushort4v o;
    o[0] = f2bf(v.x); o[1] = f2bf(v.y); o[2] = f2bf(v.z); o[3] = f2bf(v.w);
    ((ushort4v*)d)[i] = o;
}

// ---------------- GroupNorm stats: one block per (b, group) ----------------
__global__ void gn_stats(const float* __restrict__ x, float* __restrict__ stats) {
    int bg = blockIdx.x;                 // 0..127
    int b = bg >> 5, g = bg & 31;
    const float4* p = (const float4*)(x + ((size_t)b * CCH + g * 16) * HW);  // 16 ch * 4096 contiguous
    float s = 0.f, ss = 0.f;
    for (int i = threadIdx.x; i < 16384; i += 256) {
        float4 v = p[i];
        s  += v.x + v.y + v.z + v.w;
        ss += v.x * v.x + v.y * v.y + v.z * v.z + v.w * v.w;
    }
    #pragma unroll
    for (int off = 32; off > 0; off >>= 1) {
        s  += __shfl_down(s, off, 64);
        ss += __shfl_down(ss, off, 64);
    }
    __shared__ float sm[4], sm2[4];
    int wid = threadIdx.x >> 6;
    if ((threadIdx.x & 63) == 0) { sm[wid] = s; sm2[wid] = ss; }
    __syncthreads();
    if (threadIdx.x == 0) {
        float ts = sm[0] + sm[1] + sm[2] + sm[3];
        float tss = sm2[0] + sm2[1] + sm2[2] + sm2[3];
        float mean = ts * (1.f / 65536.f);
        float var = tss * (1.f / 65536.f) - mean * mean;
        stats[bg * 2] = mean;
        stats[bg * 2 + 1] = rsqrtf(var + 1e-5f);
    }
}

// ---------------- normalize + transpose -> XT[b, s, c] bf16 ----------------
__global__ void gn_apply(const float* __restrict__ x, const float* __restrict__ gnw,
                         const float* __restrict__ gnb, const float* __restrict__ stats,
                         unsigned short* __restrict__ xt) {
    int s = blockIdx.x * 256 + threadIdx.x;   // 0..4095
    int g = blockIdx.y, b = blockIdx.z;
    float mean = stats[(b * 32 + g) * 2];
    float rstd = stats[(b * 32 + g) * 2 + 1];
    const float* xb = x + ((size_t)b * CCH + g * 16) * HW + s;
    unsigned short outv[16];
    #pragma unroll
    for (int cl = 0; cl < 16; cl++) {
        int c = g * 16 + cl;
        float v = xb[(size_t)cl * HW];                       // lanes->consecutive s: coalesced
        v = (v - mean) * rstd * gnw[c] + gnb[c];
        outv[cl] = f2bf(v);
    }
    unsigned short* dst = xt + ((size_t)b * HW + s) * CCH + g * 16;   // 32B contiguous per thread
    *(ushort8v*)dst       = *(ushort8v*)&outv[0];
    *(ushort8v*)(dst + 8) = *(ushort8v*)&outv[8];
}

// ---------------- NT GEMM: C[m,n] = sum_k A[m,k] B[n,k], K=512 ----------------
// MODE 0: C bf16 [m,n], bias per-col n, *scale      (single projection)
// MODE 1: C fp32 [m,n], bias per-row m, + residual  (output projection + residual)
// MODE 2: C bf16 [m,n], bias per-row m              (V projection, stored transposed)
// MODE 3: dual-launch over z: z=0 -> (bias, scale); z=1 -> (resid-as-bias, 1.0)
//         with B and C strided by z (Q and K projections fused into one dispatch).
//
// m97 structure (this round): global_load_lds DMA staging into LINEAR [128][64]-ushort LDS
// tiles (no pad -- DMA dest must be linear). Bank spread via XOR on the per-lane GLOBAL
// source granule (g ^= row&7) with the matching XOR on the read side (both-sides rule).
// Single buffer, 2 barriers/step; LDS 32.8KB/block + ~120 VGPR -> 3-4 blocks/CU (was 2),
// occupancy hides the DMA latency (the m97 result: DMA staging +67% over reg round-trip).
template <int MODE>
__global__ __launch_bounds__(256, 3) void gemm_nt(
    const unsigned short* __restrict__ A, long long aStride,
    const unsigned short* __restrict__ Bm, long long bStride,
    const float* __restrict__ bias, float scale,
    const float* __restrict__ resid, long long rStride,
    void* __restrict__ Cp, long long cStride, int ldc) {
    __shared__ __align__(16) unsigned short lA[128 * 64];
    __shared__ __align__(16) unsigned short lB[128 * 64];
    const int tid = threadIdx.x;
    const int lane = tid & 63;
    const int wid = tid >> 6;
    const int z = blockIdx.z;
    const unsigned short* Ab = A + (size_t)z * aStride + (size_t)blockIdx.x * 128 * 512;
    const unsigned short* Bb = Bm + (size_t)z * bStride + (size_t)blockIdx.y * 128 * 512;

    floatx4 acc[4][4];
    #pragma unroll
    for (int i = 0; i < 4; i++)
        #pragma unroll
        for (int j = 0; j < 4; j++) acc[i][j] = (floatx4)0.f;

    const int wm = (wid >> 1) * 64;
    const int wn = (wid & 1) * 64;
    const int l15 = lane & 15;
    const int l4 = lane >> 4;
    const int sxr = l15 & 7;              // read-side row-XOR key

    // DMA source offsets: slot (row, g_slot) <- global granule (row, g_slot ^ (row&7))
    size_t srcOff[4];
    int dstBase[4];
    #pragma unroll
    for (int n = 0; n < 4; n++) {
        int row = n * 32 + (tid >> 3);
        int g = tid & 7;
        srcOff[n] = (size_t)row * 512 + (size_t)((g ^ (row & 7)) << 3);
        dstBase[n] = (n * 256 + wid * 64) * 8;   // wave-uniform; HW adds lane*16B
    }

    #pragma unroll 1
    for (int t = 0; t < 8; t++) {
        int k0 = t * 64;
        #pragma unroll
        for (int n = 0; n < 4; n++) gload_lds16(&Ab[srcOff[n] + k0], lA + dstBase[n]);
        #pragma unroll
        for (int n = 0; n < 4; n++) gload_lds16(&Bb[srcOff[n] + k0], lB + dstBase[n]);
        __syncthreads();   // drains DMA (vmcnt) + publishes the tile
        #pragma unroll
        for (int kk = 0; kk < 2; kk++) {
            short8 af[4], bf[4];
            #pragma unroll
            for (int i = 0; i < 4; i++)
                af[i] = *(const short8*)&lA[(wm + i * 16 + l15) * 64 + (((kk * 4 + l4) ^ sxr) << 3)];
            #pragma unroll
            for (int j = 0; j < 4; j++)
                bf[j] = *(const short8*)&lB[(wn + j * 16 + l15) * 64 + (((kk * 4 + l4) ^ sxr) << 3)];
            #pragma unroll
            for (int i = 0; i < 4; i++)
                #pragma unroll
                for (int j = 0; j < 4; j++)
                    acc[i][j] = __builtin_amdgcn_mfma_f32_16x16x32_bf16(af[i], bf[j], acc[i][j], 0, 0, 0);
        }
        if (t < 7) __syncthreads();   // all reads done before next step's DMA overwrites
    }

    long long m0 = (long long)blockIdx.x * 128 + wm;
    long long n0 = (long long)blockIdx.y * 128 + wn;
    if (MODE == 0 || MODE == 3) {
        unsigned short* C = (unsigned short*)Cp + (size_t)z * cStride;
        const float* bptr = (MODE == 3 && z == 1) ? resid : bias;
        float sc = (MODE == 3 && z == 1) ? 1.f : scale;
        #pragma unroll
        for (int i = 0; i < 4; i++)
            #pragma unroll
            for (int j = 0; j < 4; j++) {
                long long col = n0 + j * 16 + l15;
                float bv = bptr[col];
                #pragma unroll
                for (int r = 0; r < 4; r++) {
                    long long row = m0 + i * 16 + l4 * 4 + r;    // D: row=(lane>>4)*4+reg, col=lane&15
                    C[row * ldc + col] = f2bf((acc[i][j][r] + bv) * sc);
                }
            }
    } else if (MODE == 1) {
        float* C = (float*)Cp + (size_t)z * cStride;
        const float* R = resid + (size_t)z * rStride;
        #pragma unroll
        for (int i = 0; i < 4; i++)
            #pragma unroll
            for (int j = 0; j < 4; j++)
                #pragma unroll
                for (int r = 0; r < 4; r++) {
                    long long row = m0 + i * 16 + l4 * 4 + r;    // row = output channel o
                    long long col = n0 + j * 16 + l15;           // col = spatial s (coalesced)
                    C[row * ldc + col] = acc[i][j][r] + bias[row] + R[row * ldc + col];
                }
    } else {
        unsigned short* C = (unsigned short*)Cp + (size_t)z * cStride;
        #pragma unroll
        for (int i = 0; i < 4; i++)
            #pragma unroll
            for (int j = 0; j < 4; j++)
                #pragma unroll
                for (int r = 0; r < 4; r++) {
                    long long row = m0 + i * 16 + l4 * 4 + r;    // row = channel c (V^T layout)
                    long long col = n0 + j * 16 + l15;           // col = spatial s
                    C[row * ldc + col] = f2bf(acc[i][j][r] + bias[row]);
                }
    }
}

// ---------------- flash attention (no-max, 32x32 MFMA, DMA-staged, PV||QK fused) ----------------
// REVERTED to the Round-5 kernel verbatim (best measured: attn 141.2us, VGPR 108, no spill).
// One block per (q-tile 128, head, batch). Q pre-scaled by log2(e)/sqrt(hd) -> p = exp2(S).
//
// Staging via global_load_lds (async DMA): linear LDS dest, XOR-swizzled per-lane GLOBAL source.
// Pipeline (1 barrier/kt): K consumed one iter AHEAD of V ->
//   iter kt: [DMA V(kt+1)->lvNxt, DMA K(kt+2)->kWrite] [pack(kt)] [PV(kt, lvCur) || QK(kt+1, kRead)]
//            [barrier] [swap]
__global__ __launch_bounds__(256, 2) void attn_kern(
    const unsigned short* __restrict__ Qb, const unsigned short* __restrict__ Kb,
    const unsigned short* __restrict__ Vt, unsigned short* __restrict__ Ob) {
    __shared__ __align__(16) unsigned short lk0[8192], lk1[8192];   // K tiles [64 rows][128 d] (swizzled slots)
    __shared__ __align__(16) unsigned short lv0[8192], lv1[8192];   // V tiles [128 d][64 t]   (swizzled slots)
    const int tid = threadIdx.x;
    const int lane = tid & 63;
    const int w = tid >> 6;
    const int l31 = lane & 31;
    const int l1 = lane >> 5;
    const int q0 = blockIdx.x * 128;
    const int h = blockIdx.y, b = blockIdx.z;
    const size_t headOff = (size_t)h * HD;
    const size_t batchRow = (size_t)b * HW;
    const unsigned short* VtB = Vt + ((size_t)b * CCH + headOff) * HW;  // [d][s]

    // per-thread DMA source indices (ushort units); advance by tile offset each iter
    size_t kSrc[4], vSrc[4];
    #pragma unroll
    for (int n = 0; n < 4; n++) {
        int row = w * 16 + n * 4 + (lane >> 4);
        int sk = ((row & 7) << 1) | ((row >> 3) & 1);
        int jk = (lane & 15) ^ sk;
        kSrc[n] = (batchRow + row) * 512 + headOff + jk * 8;
        int d = w * 32 + n * 8 + (lane >> 3);
        int jv = (lane & 7) ^ (d & 7);
        vSrc[n] = (size_t)d * HW + jv * 8;
    }
    const int ldsOff = w * 4 * 512;   // wave-uniform LDS chunk base (ushorts); +n*512 per load

    // read-side swizzle constants
    const int sk0 = ((l31 & 7) << 1) | ((l31 >> 3) & 1);
    const int sv0 = l31 & 7;

    // Q fragments in registers: wave w owns q-rows [w*32, w*32+32); B[n=q=l31][k=d=kd*16+l1*8+e]
    short8 qf[8];
    #pragma unroll
    for (int kd = 0; kd < 8; kd++)
        qf[kd] = *(const short8*)&Qb[(batchRow + q0 + w * 32 + l31) * 512
                                     + headOff + kd * 16 + l1 * 8];

    // all-ones B-fragment -> D[m][n] = rowsum(A[m][:])
    short8 onesf;
    #pragma unroll
    for (int e = 0; e < 8; e++) onesf[e] = (short)0x3F80;

    floatx16 acc_o[4];   // O[q][d]: col d = dj*32+l31, row q = (reg&3)+8*(reg>>2)+4*l1
    floatx16 acc_l;      // lsum[q]: same row pattern, every col identical
    acc_l = (floatx16)0.f;
    #pragma unroll
    for (int dj = 0; dj < 4; dj++) acc_o[dj] = (floatx16)0.f;

    // prologue: DMA K(0)->lk0, K(1)->lk1, V(0)->lv0; publish; QK(0); publish-consumption barrier
    #pragma unroll
    for (int n = 0; n < 4; n++) gload_lds16(&Kb[kSrc[n]], lk0 + ldsOff + n * 512);
    #pragma unroll
    for (int n = 0; n < 4; n++) gload_lds16(&Kb[kSrc[n] + (size_t)64 * 512], lk1 + ldsOff + n * 512);
    #pragma unroll
    for (int n = 0; n < 4; n++) gload_lds16(&VtB[vSrc[n]], lv0 + ldsOff + n * 512);
    __syncthreads();

    floatx16 sa0 = (floatx16)0.f, sa1 = (floatx16)0.f;
    #pragma unroll
    for (int kd = 0; kd < 8; kd++) {
        int xk = ((kd * 2 + l1) ^ sk0) * 8;
        short8 kf0 = *(const short8*)&lk0[l31 * 128 + xk];
        short8 kf1 = *(const short8*)&lk0[l31 * 128 + xk + 4096];
        sa0 = __builtin_amdgcn_mfma_f32_32x32x16_bf16(kf0, qf[kd], sa0, 0, 0, 0);
        sa1 = __builtin_amdgcn_mfma_f32_32x32x16_bf16(kf1, qf[kd], sa1, 0, 0, 0);
    }
    __syncthreads();   // all waves done reading lk0 before iter 0's DMA K(2)->lk0

    unsigned short* lvCur = lv0;  unsigned short* lvNxt = lv1;
    unsigned short* kRead = lk1;  unsigned short* kWrite = lk0;

    #pragma unroll 1
    for (int kt = 0; kt < 63; kt++) {
        // issue async DMA: V(kt+1) -> lvNxt, K(kt+2) -> kWrite (targets consumed >=1 barrier ago;
        // kt=62's K(64) reads harmless in-workspace bytes and is never consumed)
        {
            size_t tv = (size_t)(kt + 1) * 64;
            size_t tk = (size_t)(kt + 2) * 64 * 512;
            #pragma unroll
            for (int n = 0; n < 4; n++) gload_lds16(&VtB[vSrc[n] + tv], lvNxt + ldsOff + n * 512);
            #pragma unroll
            for (int n = 0; n < 4; n++) gload_lds16(&Kb[kSrc[n] + tk], kWrite + ldsOff + n * 512);
        }

        // ---- pack(kt): p = exp2(S) in-register, cvt_pk pairs + permlane32_swap -> paf[0..3] ----
        short8 paf[4];
        #pragma unroll
        for (int r = 0; r < 16; r++) sa0[r] = __builtin_amdgcn_exp2f(sa0[r]);
        #pragma unroll
        for (int r = 0; r < 16; r++) sa1[r] = __builtin_amdgcn_exp2f(sa1[r]);
        #pragma unroll
        for (int tb = 0; tb < 2; tb++) {
            const floatx16& sa = tb ? sa1 : sa0;
            unsigned int wv[4][2];
            #pragma unroll
            for (int g = 0; g < 4; g++) {
                asm("v_cvt_pk_bf16_f32 %0, %1, %2" : "=v"(wv[g][0])
                    : "v"(sa[4 * g + 0]), "v"(sa[4 * g + 1]));
                asm("v_cvt_pk_bf16_f32 %0, %1, %2" : "=v"(wv[g][1])
                    : "v"(sa[4 * g + 2]), "v"(sa[4 * g + 3]));
            }
            #pragma unroll
            for (int hh = 0; hh < 2; hh++) {
                unsigned int a0 = wv[2 * hh][0], b0 = wv[2 * hh + 1][0];
                unsigned int a1 = wv[2 * hh][1], b1 = wv[2 * hh + 1][1];
                asm("v_permlane32_swap_b32 %0, %1" : "+v"(a0), "+v"(b0));
                asm("v_permlane32_swap_b32 %0, %1" : "+v"(a1), "+v"(b1));
                union { unsigned int u[4]; short8 s8; } f;
                f.u[0] = a0; f.u[1] = a1; f.u[2] = b0; f.u[3] = b1;
                paf[2 * tb + hh] = f.s8;
            }
        }

        // ---- fused MFMA cluster: PV(kt) from lvCur  ||  QK(kt+1) from kRead ----
        sa0 = (floatx16)0.f; sa1 = (floatx16)0.f;
        __builtin_amdgcn_s_setprio(1);
        #pragma unroll
        for (int u = 0; u < 4; u++) {
            #pragma unroll
            for (int q2 = 0; q2 < 2; q2++) {
                int kd = u * 2 + q2;
                int xk = ((kd * 2 + l1) ^ sk0) * 8;
                short8 kf0 = *(const short8*)&kRead[l31 * 128 + xk];
                short8 kf1 = *(const short8*)&kRead[l31 * 128 + xk + 4096];
                sa0 = __builtin_amdgcn_mfma_f32_32x32x16_bf16(kf0, qf[kd], sa0, 0, 0, 0);
                sa1 = __builtin_amdgcn_mfma_f32_32x32x16_bf16(kf1, qf[kd], sa1, 0, 0, 0);
            }
            acc_l = __builtin_amdgcn_mfma_f32_32x32x16_bf16(paf[u], onesf, acc_l, 0, 0, 0);
            int xv = ((u * 2 + l1) ^ sv0) * 8;
            #pragma unroll
            for (int dj = 0; dj < 4; dj++) {
                short8 vv = *(const short8*)&lvCur[dj * 2048 + l31 * 64 + xv];
                acc_o[dj] = __builtin_amdgcn_mfma_f32_32x32x16_bf16(paf[u], vv, acc_o[dj], 0, 0, 0);
            }
        }
        __builtin_amdgcn_s_setprio(0);

        __syncthreads();   // drains this wave's DMA (vmcnt) + publishes tiles V(kt+1), K(kt+2)
        unsigned short* t;
        t = lvCur; lvCur = lvNxt; lvNxt = t;
        t = kRead; kRead = kWrite; kWrite = t;
    }

    // ---- tail kt=63: pack + PV only ----
    {
        short8 paf[4];
        #pragma unroll
        for (int r = 0; r < 16; r++) sa0[r] = __builtin_amdgcn_exp2f(sa0[r]);
        #pragma unroll
        for (int r = 0; r < 16; r++) sa1[r] = __builtin_amdgcn_exp2f(sa1[r]);
        #pragma unroll
        for (int tb = 0; tb < 2; tb++) {
            const floatx16& sa = tb ? sa1 : sa0;
            unsigned int wv[4][2];
            #pragma unroll
            for (int g = 0; g < 4; g++) {
                asm("v_cvt_pk_bf16_f32 %0, %1, %2" : "=v"(wv[g][0])
                    : "v"(sa[4 * g + 0]), "v"(sa[4 * g + 1]));
                asm("v_cvt_pk_bf16_f32 %0, %1, %2" : "=v"(wv[g][1])
                    : "v"(sa[4 * g + 2]), "v"(sa[4 * g + 3]));
            }
            #pragma unroll
            for (int hh = 0; hh < 2; hh++) {
                unsigned int a0 = wv[2 * hh][0], b0 = wv[2 * hh + 1][0];
                unsigned int a1 = wv[2 * hh][1], b1 = wv[2 * hh + 1][1];
                asm("v_permlane32_swap_b32 %0, %1" : "+v"(a0), "+v"(b0));
                asm("v_permlane32_swap_b32 %0, %1" : "+v"(a1), "+v"(b1));
                union { unsigned int u[4]; short8 s8; } f;
                f.u[0] = a0; f.u[1] = a1; f.u[2] = b0; f.u[3] = b1;
                paf[2 * tb + hh] = f.s8;
            }
        }
        __builtin_amdgcn_s_setprio(1);
        #pragma unroll
        for (int u = 0; u < 4; u++) {
            acc_l = __builtin_amdgcn_mfma_f32_32x32x16_bf16(paf[u], onesf, acc_l, 0, 0, 0);
            int xv = ((u * 2 + l1) ^ sv0) * 8;
            #pragma unroll
            for (int dj = 0; dj < 4; dj++) {
                short8 vv = *(const short8*)&lvCur[dj * 2048 + l31 * 64 + xv];
                acc_o[dj] = __builtin_amdgcn_mfma_f32_32x32x16_bf16(paf[u], vv, acc_o[dj], 0, 0, 0);
            }
        }
        __builtin_amdgcn_s_setprio(0);
    }

    // epilogue: acc_l[reg] holds lsum for exactly the q-row acc_o[.][reg] holds
    #pragma unroll
    for (int g = 0; g < 4; g++)
        #pragma unroll
        for (int p = 0; p < 4; p++) {
            int reg = 4 * g + p;
            float rl = 1.f / acc_l[reg];
            int qr = p + 8 * g + 4 * l1;
            size_t row = batchRow + q0 + w * 32 + qr;
            #pragma unroll
            for (int dj = 0; dj < 4; dj++)
                Ob[row * 512 + headOff + dj * 32 + l31] = f2bf(acc_o[dj][reg] * rl);
        }
}

extern "C" void kernel_launch(void* const* d_in, const int* in_sizes, int n_in,
                              void* d_out, int out_size, void* d_ws, size_t ws_size,
                              hipStream_t stream) {
    const float* x   = (const float*)d_in[0];
    const float* gnw = (const float*)d_in[1];
    const float* gnb = (const float*)d_in[2];
    const float* wq  = (const float*)d_in[3];
    const float* bq  = (const float*)d_in[4];
    const float* wk  = (const float*)d_in[5];
    const float* bk  = (const float*)d_in[6];
    const float* wv  = (const float*)d_in[7];
    const float* bv  = (const float*)d_in[8];
    const float* wp  = (const float*)d_in[9];
    const float* bp  = (const float*)d_in[10];
    float* out = (float*)d_out;

    const size_t NE = (size_t)NB * HW * CCH;          // 8388608 elements
    unsigned short* ws16 = (unsigned short*)d_ws;
    unsigned short* XT = ws16;                        // x_n transposed (b,s,c); reused as attn O
    unsigned short* Qb = ws16 + NE;
    unsigned short* Kb = ws16 + 2 * NE;
    unsigned short* Vt = ws16 + 3 * NE;               // V transposed: [b][c][s]
    unsigned short* Wb = ws16 + 4 * NE;               // 4 x 262144 bf16 weights
    float* stats = (float*)(ws16 + 4 * NE + 4 * 262144);

    // fold log2(e) into the attention scale so the kernel uses exp2 directly
    const float qscale = 0.08838834764831845f * 1.4426950408889634f;

    conv_w<<<dim3(256, 4), 256, 0, stream>>>(wq, wk, wv, wp, Wb);
    gn_stats<<<128, 256, 0, stream>>>(x, stats);
    gn_apply<<<dim3(16, 32, 4), 256, 0, stream>>>(x, gnw, gnb, stats, XT);

    // Q and K projections fused into one dispatch: z=0 -> Q (bias bq, *qscale), z=1 -> K (bias bk)
    gemm_nt<3><<<dim3(128, 4, 2), 256, 0, stream>>>(XT, 0, Wb, 262144, bq, qscale, bk, 0,
                                                    Qb, (long long)NE, 512);
    // V stored transposed: Vt[b][c][s] = Wv @ XT[b]^T
    gemm_nt<2><<<dim3(4, 32, 4), 256, 0, stream>>>(Wb + 2 * 262144, 0, XT, (long long)HW * 512, bv, 1.f,
                                                   nullptr, 0, Vt, (long long)CCH * HW, HW);

    unsigned short* Ob = XT;   // XT dead after QKV; reuse for attention output (b,s,c)
    attn_kern<<<dim3(32, NH, NB), 256, 0, stream>>>(Qb, Kb, Vt, Ob);

    // out[b,o,s] = sum_c wp[o,c] * Ob[b,s,c] + bp[o] + x[b,o,s]
    gemm_nt<1><<<dim3(4, 32, 4), 256, 0, stream>>>(Wb + 3 * 262144, 0, Ob, (long long)HW * 512, bp, 1.f,
                                                   x, (long long)CCH * HW, out, (long long)CCH * HW, HW);
}

// Round 9
// 327.464 us; speedup vs baseline: 1.1312x; 1.0261x over previous
//
#include <hip/hip_runtime.h>
#include <math.h>

typedef __attribute__((ext_vector_type(8))) short short8;      // 8 bf16 (4 VGPRs) MFMA operand
typedef __attribute__((ext_vector_type(4))) float floatx4;     // 16x16 MFMA accumulator
typedef __attribute__((ext_vector_type(16))) float floatx16;   // 32x32 MFMA accumulator
typedef __attribute__((ext_vector_type(8))) unsigned short ushort8v;
typedef __attribute__((ext_vector_type(4))) unsigned short ushort4v;

#define HW 4096
#define CCH 512
#define NB 4
#define NH 4
#define HD 128

__device__ __forceinline__ unsigned short f2bf(float f) {
    union { float f; unsigned int u; } c; c.f = f;
    unsigned int u = c.u;
    u += 0x7FFFu + ((u >> 16) & 1u);   // round-to-nearest-even
    return (unsigned short)(u >> 16);
}

// async global->LDS DMA, 16B per lane. LDS dest = wave-uniform base + lane*16 (linear);
// swizzled layouts are achieved by permuting the per-lane GLOBAL source address.
__device__ __forceinline__ void gload_lds16(const unsigned short* g, unsigned short* l) {
    __builtin_amdgcn_global_load_lds(
        (const __attribute__((address_space(1))) unsigned int*)g,
        (__attribute__((address_space(3))) unsigned int*)l, 16, 0, 0);
}

// ---------------- weights fp32 -> bf16 ----------------
__global__ void conv_w(const float* __restrict__ w0, const float* __restrict__ w1,
                       const float* __restrict__ w2, const float* __restrict__ w3,
                       unsigned short* __restrict__ dst) {
    const float* src = blockIdx.y == 0 ? w0 : blockIdx.y == 1 ? w1 : blockIdx.y == 2 ? w2 : w3;
    unsigned short* d = dst + (size_t)blockIdx.y * 262144;
    int i = blockIdx.x * 256 + threadIdx.x;          // float4 index, 65536 total
    float4 v = ((const float4*)src)[i];
    ushort4v o;
    o[0] = f2bf(v.x); o[1] = f2bf(v.y); o[2] = f2bf(v.z); o[3] = f2bf(v.w);
    ((ushort4v*)d)[i] = o;
}

// ---------------- GroupNorm stats: one block per (b, group) ----------------
__global__ void gn_stats(const float* __restrict__ x, float* __restrict__ stats) {
    int bg = blockIdx.x;                 // 0..127
    int b = bg >> 5, g = bg & 31;
    const float4* p = (const float4*)(x + ((size_t)b * CCH + g * 16) * HW);  // 16 ch * 4096 contiguous
    float s = 0.f, ss = 0.f;
    for (int i = threadIdx.x; i < 16384; i += 256) {
        float4 v = p[i];
        s  += v.x + v.y + v.z + v.w;
        ss += v.x * v.x + v.y * v.y + v.z * v.z + v.w * v.w;
    }
    #pragma unroll
    for (int off = 32; off > 0; off >>= 1) {
        s  += __shfl_down(s, off, 64);
        ss += __shfl_down(ss, off, 64);
    }
    __shared__ float sm[4], sm2[4];
    int wid = threadIdx.x >> 6;
    if ((threadIdx.x & 63) == 0) { sm[wid] = s; sm2[wid] = ss; }
    __syncthreads();
    if (threadIdx.x == 0) {
        float ts = sm[0] + sm[1] + sm[2] + sm[3];
        float tss = sm2[0] + sm2[1] + sm2[2] + sm2[3];
        float mean = ts * (1.f / 65536.f);
        float var = tss * (1.f / 65536.f) - mean * mean;
        stats[bg * 2] = mean;
        stats[bg * 2 + 1] = rsqrtf(var + 1e-5f);
    }
}

// ---------------- normalize + transpose -> XT[b, s, c] bf16 ----------------
__global__ void gn_apply(const float* __restrict__ x, const float* __restrict__ gnw,
                         const float* __restrict__ gnb, const float* __restrict__ stats,
                         unsigned short* __restrict__ xt) {
    int s = blockIdx.x * 256 + threadIdx.x;   // 0..4095
    int g = blockIdx.y, b = blockIdx.z;
    float mean = stats[(b * 32 + g) * 2];
    float rstd = stats[(b * 32 + g) * 2 + 1];
    const float* xb = x + ((size_t)b * CCH + g * 16) * HW + s;
    unsigned short outv[16];
    #pragma unroll
    for (int cl = 0; cl < 16; cl++) {
        int c = g * 16 + cl;
        float v = xb[(size_t)cl * HW];                       // lanes->consecutive s: coalesced
        v = (v - mean) * rstd * gnw[c] + gnb[c];
        outv[cl] = f2bf(v);
    }
    unsigned short* dst = xt + ((size_t)b * HW + s) * CCH + g * 16;   // 32B contiguous per thread
    *(ushort8v*)dst       = *(ushort8v*)&outv[0];
    *(ushort8v*)(dst + 8) = *(ushort8v*)&outv[8];
}

// ---------------- NT GEMM: C[m,n] = sum_k A[m,k] B[n,k], K=512 ----------------
// MODE 0: C bf16 [m,n], bias per-col n, *scale      (single projection)
// MODE 1: C fp32 [m,n], bias per-row m, + residual  (output projection + residual)
// MODE 2: C bf16 [m,n], bias per-row m              (V projection, stored transposed)
// MODE 3: dual-launch over z: z=0 -> (bias, scale); z=1 -> (resid-as-bias, 1.0)
//         with B and C strided by z (Q and K projections fused into one dispatch).
//
// m97 structure: global_load_lds DMA staging into LINEAR [128][64]-ushort LDS tiles.
// Bank spread via XOR on the per-lane GLOBAL source granule (g ^= row&7) with the matching
// XOR on the read side (both-sides rule). Single buffer, 2 barriers/step; 32.8KB LDS.
template <int MODE>
__global__ __launch_bounds__(256, 3) void gemm_nt(
    const unsigned short* __restrict__ A, long long aStride,
    const unsigned short* __restrict__ Bm, long long bStride,
    const float* __restrict__ bias, float scale,
    const float* __restrict__ resid, long long rStride,
    void* __restrict__ Cp, long long cStride, int ldc) {
    __shared__ __align__(16) unsigned short lA[128 * 64];
    __shared__ __align__(16) unsigned short lB[128 * 64];
    const int tid = threadIdx.x;
    const int lane = tid & 63;
    const int wid = tid >> 6;
    const int z = blockIdx.z;
    const unsigned short* Ab = A + (size_t)z * aStride + (size_t)blockIdx.x * 128 * 512;
    const unsigned short* Bb = Bm + (size_t)z * bStride + (size_t)blockIdx.y * 128 * 512;

    floatx4 acc[4][4];
    #pragma unroll
    for (int i = 0; i < 4; i++)
        #pragma unroll
        for (int j = 0; j < 4; j++) acc[i][j] = (floatx4)0.f;

    const int wm = (wid >> 1) * 64;
    const int wn = (wid & 1) * 64;
    const int l15 = lane & 15;
    const int l4 = lane >> 4;
    const int sxr = l15 & 7;              // read-side row-XOR key

    // DMA source offsets: slot (row, g_slot) <- global granule (row, g_slot ^ (row&7))
    size_t srcOff[4];
    int dstBase[4];
    #pragma unroll
    for (int n = 0; n < 4; n++) {
        int row = n * 32 + (tid >> 3);
        int g = tid & 7;
        srcOff[n] = (size_t)row * 512 + (size_t)((g ^ (row & 7)) << 3);
        dstBase[n] = (n * 256 + wid * 64) * 8;   // wave-uniform; HW adds lane*16B
    }

    #pragma unroll 1
    for (int t = 0; t < 8; t++) {
        int k0 = t * 64;
        #pragma unroll
        for (int n = 0; n < 4; n++) gload_lds16(&Ab[srcOff[n] + k0], lA + dstBase[n]);
        #pragma unroll
        for (int n = 0; n < 4; n++) gload_lds16(&Bb[srcOff[n] + k0], lB + dstBase[n]);
        __syncthreads();   // drains DMA (vmcnt) + publishes the tile
        #pragma unroll
        for (int kk = 0; kk < 2; kk++) {
            short8 af[4], bf[4];
            #pragma unroll
            for (int i = 0; i < 4; i++)
                af[i] = *(const short8*)&lA[(wm + i * 16 + l15) * 64 + (((kk * 4 + l4) ^ sxr) << 3)];
            #pragma unroll
            for (int j = 0; j < 4; j++)
                bf[j] = *(const short8*)&lB[(wn + j * 16 + l15) * 64 + (((kk * 4 + l4) ^ sxr) << 3)];
            #pragma unroll
            for (int i = 0; i < 4; i++)
                #pragma unroll
                for (int j = 0; j < 4; j++)
                    acc[i][j] = __builtin_amdgcn_mfma_f32_16x16x32_bf16(af[i], bf[j], acc[i][j], 0, 0, 0);
        }
        if (t < 7) __syncthreads();   // all reads done before next step's DMA overwrites
    }

    long long m0 = (long long)blockIdx.x * 128 + wm;
    long long n0 = (long long)blockIdx.y * 128 + wn;
    if (MODE == 0 || MODE == 3) {
        unsigned short* C = (unsigned short*)Cp + (size_t)z * cStride;
        const float* bptr = (MODE == 3 && z == 1) ? resid : bias;
        float sc = (MODE == 3 && z == 1) ? 1.f : scale;
        #pragma unroll
        for (int i = 0; i < 4; i++)
            #pragma unroll
            for (int j = 0; j < 4; j++) {
                long long col = n0 + j * 16 + l15;
                float bv = bptr[col];
                #pragma unroll
                for (int r = 0; r < 4; r++) {
                    long long row = m0 + i * 16 + l4 * 4 + r;    // D: row=(lane>>4)*4+reg, col=lane&15
                    C[row * ldc + col] = f2bf((acc[i][j][r] + bv) * sc);
                }
            }
    } else if (MODE == 1) {
        float* C = (float*)Cp + (size_t)z * cStride;
        const float* R = resid + (size_t)z * rStride;
        #pragma unroll
        for (int i = 0; i < 4; i++)
            #pragma unroll
            for (int j = 0; j < 4; j++)
                #pragma unroll
                for (int r = 0; r < 4; r++) {
                    long long row = m0 + i * 16 + l4 * 4 + r;    // row = output channel o
                    long long col = n0 + j * 16 + l15;           // col = spatial s (coalesced)
                    C[row * ldc + col] = acc[i][j][r] + bias[row] + R[row * ldc + col];
                }
    } else {
        unsigned short* C = (unsigned short*)Cp + (size_t)z * cStride;
        #pragma unroll
        for (int i = 0; i < 4; i++)
            #pragma unroll
            for (int j = 0; j < 4; j++)
                #pragma unroll
                for (int r = 0; r < 4; r++) {
                    long long row = m0 + i * 16 + l4 * 4 + r;    // row = channel c (V^T layout)
                    long long col = n0 + j * 16 + l15;           // col = spatial s
                    C[row * ldc + col] = f2bf(acc[i][j][r] + bias[row]);
                }
    }
}

// ---------------- flash attention (no-max, 32x32 MFMA, DMA-staged, q-tile 256) ----------------
// One block per (q-tile 256, head, batch): 512 threads, 8 waves x 32 q-rows.
// WHY 256: the q-128 version re-read K+V 32x per (b,h) -> ~7.2 TB/s aggregate tile traffic,
// at the Infinity-Cache bandwidth ceiling (only 140MB is HBM; L2/XCD working set ~16MB >> 4MB).
// q-256 halves the demand, and the block decode below pins each (b,h) group's 16 q-tiles to
// ONE XCD (bid = g + 16*qt -> bid%8 = g%8 under round-robin XCD placement), making the per-XCD
// working set 2 groups x 2MB = 4MB = exactly L2 -> K/V served at L2 speed.
// Per-wave structure is byte-identical to the proven R5/R8 kernel (fragments, swizzles, fused
// PV||QK cluster, MFMA rowsum); only DMA chunk ownership changes (2 chunks/wave of 8 waves).
// Grid = 256 blocks = exactly 1/CU (no tail). VGPR ~108, LDS 64KB.
__global__ __launch_bounds__(512, 2) void attn_kern(
    const unsigned short* __restrict__ Qb, const unsigned short* __restrict__ Kb,
    const unsigned short* __restrict__ Vt, unsigned short* __restrict__ Ob) {
    __shared__ __align__(16) unsigned short lk0[8192], lk1[8192];   // K tiles [64 rows][128 d] (swizzled slots)
    __shared__ __align__(16) unsigned short lv0[8192], lv1[8192];   // V tiles [128 d][64 t]   (swizzled slots)
    const int tid = threadIdx.x;
    const int lane = tid & 63;
    const int w = tid >> 6;            // 0..7
    const int l31 = lane & 31;
    const int l1 = lane >> 5;
    const int bid = blockIdx.x;
    const int g = bid & 15;            // (b,h) group: all 16 q-tiles of g share bid%8 -> one XCD
    const int qt = bid >> 4;           // q-tile 0..15
    const int h = g & 3, b = g >> 2;
    const int q0 = qt * 256;
    const size_t headOff = (size_t)h * HD;
    const size_t batchRow = (size_t)b * HW;
    const unsigned short* VtB = Vt + ((size_t)b * CCH + headOff) * HW;  // [d][s]

    // per-thread DMA source indices (ushort units); wave w owns chunks {2w, 2w+1} of each tile
    size_t kSrc[2], vSrc[2];
    #pragma unroll
    for (int n = 0; n < 2; n++) {
        int row = w * 8 + n * 4 + (lane >> 4);
        int sk = ((row & 7) << 1) | ((row >> 3) & 1);
        int jk = (lane & 15) ^ sk;
        kSrc[n] = (batchRow + row) * 512 + headOff + jk * 8;
        int d = w * 16 + n * 8 + (lane >> 3);
        int jv = (lane & 7) ^ (d & 7);
        vSrc[n] = (size_t)d * HW + jv * 8;
    }
    const int ldsOff = w * 1024;   // wave-uniform LDS chunk base (ushorts); +n*512 per load

    // read-side swizzle constants
    const int sk0 = ((l31 & 7) << 1) | ((l31 >> 3) & 1);
    const int sv0 = l31 & 7;

    // Q fragments in registers: wave w owns q-rows [q0+w*32, q0+w*32+32)
    short8 qf[8];
    #pragma unroll
    for (int kd = 0; kd < 8; kd++)
        qf[kd] = *(const short8*)&Qb[(batchRow + q0 + w * 32 + l31) * 512
                                     + headOff + kd * 16 + l1 * 8];

    // all-ones B-fragment -> D[m][n] = rowsum(A[m][:])
    short8 onesf;
    #pragma unroll
    for (int e = 0; e < 8; e++) onesf[e] = (short)0x3F80;

    floatx16 acc_o[4];   // O[q][d]: col d = dj*32+l31, row q = (reg&3)+8*(reg>>2)+4*l1
    floatx16 acc_l;      // lsum[q]: same row pattern, every col identical
    acc_l = (floatx16)0.f;
    #pragma unroll
    for (int dj = 0; dj < 4; dj++) acc_o[dj] = (floatx16)0.f;

    // prologue: DMA K(0)->lk0, K(1)->lk1, V(0)->lv0; publish; QK(0); consumption barrier
    #pragma unroll
    for (int n = 0; n < 2; n++) gload_lds16(&Kb[kSrc[n]], lk0 + ldsOff + n * 512);
    #pragma unroll
    for (int n = 0; n < 2; n++) gload_lds16(&Kb[kSrc[n] + (size_t)64 * 512], lk1 + ldsOff + n * 512);
    #pragma unroll
    for (int n = 0; n < 2; n++) gload_lds16(&VtB[vSrc[n]], lv0 + ldsOff + n * 512);
    __syncthreads();

    floatx16 sa0 = (floatx16)0.f, sa1 = (floatx16)0.f;
    #pragma unroll
    for (int kd = 0; kd < 8; kd++) {
        int xk = ((kd * 2 + l1) ^ sk0) * 8;
        short8 kf0 = *(const short8*)&lk0[l31 * 128 + xk];
        short8 kf1 = *(const short8*)&lk0[l31 * 128 + xk + 4096];
        sa0 = __builtin_amdgcn_mfma_f32_32x32x16_bf16(kf0, qf[kd], sa0, 0, 0, 0);
        sa1 = __builtin_amdgcn_mfma_f32_32x32x16_bf16(kf1, qf[kd], sa1, 0, 0, 0);
    }
    __syncthreads();   // all waves done reading lk0 before iter 0's DMA K(2)->lk0

    unsigned short* lvCur = lv0;  unsigned short* lvNxt = lv1;
    unsigned short* kRead = lk1;  unsigned short* kWrite = lk0;

    #pragma unroll 1
    for (int kt = 0; kt < 63; kt++) {
        // issue async DMA: V(kt+1) -> lvNxt, K(kt+2) -> kWrite (targets consumed >=1 barrier ago;
        // kt=62's K(64) reads harmless in-workspace bytes and is never consumed)
        {
            size_t tv = (size_t)(kt + 1) * 64;
            size_t tk = (size_t)(kt + 2) * 64 * 512;
            #pragma unroll
            for (int n = 0; n < 2; n++) gload_lds16(&VtB[vSrc[n] + tv], lvNxt + ldsOff + n * 512);
            #pragma unroll
            for (int n = 0; n < 2; n++) gload_lds16(&Kb[kSrc[n] + tk], kWrite + ldsOff + n * 512);
        }

        // ---- pack(kt): p = exp2(S) in-register, cvt_pk pairs + permlane32_swap -> paf[0..3] ----
        short8 paf[4];
        #pragma unroll
        for (int r = 0; r < 16; r++) sa0[r] = __builtin_amdgcn_exp2f(sa0[r]);
        #pragma unroll
        for (int r = 0; r < 16; r++) sa1[r] = __builtin_amdgcn_exp2f(sa1[r]);
        #pragma unroll
        for (int tb = 0; tb < 2; tb++) {
            const floatx16& sa = tb ? sa1 : sa0;
            unsigned int wv[4][2];
            #pragma unroll
            for (int gg = 0; gg < 4; gg++) {
                asm("v_cvt_pk_bf16_f32 %0, %1, %2" : "=v"(wv[gg][0])
                    : "v"(sa[4 * gg + 0]), "v"(sa[4 * gg + 1]));
                asm("v_cvt_pk_bf16_f32 %0, %1, %2" : "=v"(wv[gg][1])
                    : "v"(sa[4 * gg + 2]), "v"(sa[4 * gg + 3]));
            }
            #pragma unroll
            for (int hh = 0; hh < 2; hh++) {
                unsigned int a0 = wv[2 * hh][0], b0 = wv[2 * hh + 1][0];
                unsigned int a1 = wv[2 * hh][1], b1 = wv[2 * hh + 1][1];
                asm("v_permlane32_swap_b32 %0, %1" : "+v"(a0), "+v"(b0));
                asm("v_permlane32_swap_b32 %0, %1" : "+v"(a1), "+v"(b1));
                union { unsigned int u[4]; short8 s8; } f;
                f.u[0] = a0; f.u[1] = a1; f.u[2] = b0; f.u[3] = b1;
                paf[2 * tb + hh] = f.s8;
            }
        }

        // ---- fused MFMA cluster: PV(kt) from lvCur  ||  QK(kt+1) from kRead ----
        sa0 = (floatx16)0.f; sa1 = (floatx16)0.f;
        __builtin_amdgcn_s_setprio(1);
        #pragma unroll
        for (int u = 0; u < 4; u++) {
            #pragma unroll
            for (int q2 = 0; q2 < 2; q2++) {
                int kd = u * 2 + q2;
                int xk = ((kd * 2 + l1) ^ sk0) * 8;
                short8 kf0 = *(const short8*)&kRead[l31 * 128 + xk];
                short8 kf1 = *(const short8*)&kRead[l31 * 128 + xk + 4096];
                sa0 = __builtin_amdgcn_mfma_f32_32x32x16_bf16(kf0, qf[kd], sa0, 0, 0, 0);
                sa1 = __builtin_amdgcn_mfma_f32_32x32x16_bf16(kf1, qf[kd], sa1, 0, 0, 0);
            }
            acc_l = __builtin_amdgcn_mfma_f32_32x32x16_bf16(paf[u], onesf, acc_l, 0, 0, 0);
            int xv = ((u * 2 + l1) ^ sv0) * 8;
            #pragma unroll
            for (int dj = 0; dj < 4; dj++) {
                short8 vv = *(const short8*)&lvCur[dj * 2048 + l31 * 64 + xv];
                acc_o[dj] = __builtin_amdgcn_mfma_f32_32x32x16_bf16(paf[u], vv, acc_o[dj], 0, 0, 0);
            }
        }
        __builtin_amdgcn_s_setprio(0);

        __syncthreads();   // drains this wave's DMA (vmcnt) + publishes tiles V(kt+1), K(kt+2)
        unsigned short* t;
        t = lvCur; lvCur = lvNxt; lvNxt = t;
        t = kRead; kRead = kWrite; kWrite = t;
    }

    // ---- tail kt=63: pack + PV only ----
    {
        short8 paf[4];
        #pragma unroll
        for (int r = 0; r < 16; r++) sa0[r] = __builtin_amdgcn_exp2f(sa0[r]);
        #pragma unroll
        for (int r = 0; r < 16; r++) sa1[r] = __builtin_amdgcn_exp2f(sa1[r]);
        #pragma unroll
        for (int tb = 0; tb < 2; tb++) {
            const floatx16& sa = tb ? sa1 : sa0;
            unsigned int wv[4][2];
            #pragma unroll
            for (int gg = 0; gg < 4; gg++) {
                asm("v_cvt_pk_bf16_f32 %0, %1, %2" : "=v"(wv[gg][0])
                    : "v"(sa[4 * gg + 0]), "v"(sa[4 * gg + 1]));
                asm("v_cvt_pk_bf16_f32 %0, %1, %2" : "=v"(wv[gg][1])
                    : "v"(sa[4 * gg + 2]), "v"(sa[4 * gg + 3]));
            }
            #pragma unroll
            for (int hh = 0; hh < 2; hh++) {
                unsigned int a0 = wv[2 * hh][0], b0 = wv[2 * hh + 1][0];
                unsigned int a1 = wv[2 * hh][1], b1 = wv[2 * hh + 1][1];
                asm("v_permlane32_swap_b32 %0, %1" : "+v"(a0), "+v"(b0));
                asm("v_permlane32_swap_b32 %0, %1" : "+v"(a1), "+v"(b1));
                union { unsigned int u[4]; short8 s8; } f;
                f.u[0] = a0; f.u[1] = a1; f.u[2] = b0; f.u[3] = b1;
                paf[2 * tb + hh] = f.s8;
            }
        }
        __builtin_amdgcn_s_setprio(1);
        #pragma unroll
        for (int u = 0; u < 4; u++) {
            acc_l = __builtin_amdgcn_mfma_f32_32x32x16_bf16(paf[u], onesf, acc_l, 0, 0, 0);
            int xv = ((u * 2 + l1) ^ sv0) * 8;
            #pragma unroll
            for (int dj = 0; dj < 4; dj++) {
                short8 vv = *(const short8*)&lvCur[dj * 2048 + l31 * 64 + xv];
                acc_o[dj] = __builtin_amdgcn_mfma_f32_32x32x16_bf16(paf[u], vv, acc_o[dj], 0, 0, 0);
            }
        }
        __builtin_amdgcn_s_setprio(0);
    }

    // epilogue: acc_l[reg] holds lsum for exactly the q-row acc_o[.][reg] holds
    #pragma unroll
    for (int gg = 0; gg < 4; gg++)
        #pragma unroll
        for (int p = 0; p < 4; p++) {
            int reg = 4 * gg + p;
            float rl = 1.f / acc_l[reg];
            int qr = p + 8 * gg + 4 * l1;
            size_t row = batchRow + q0 + w * 32 + qr;
            #pragma unroll
            for (int dj = 0; dj < 4; dj++)
                Ob[row * 512 + headOff + dj * 32 + l31] = f2bf(acc_o[dj][reg] * rl);
        }
}

extern "C" void kernel_launch(void* const* d_in, const int* in_sizes, int n_in,
                              void* d_out, int out_size, void* d_ws, size_t ws_size,
                              hipStream_t stream) {
    const float* x   = (const float*)d_in[0];
    const float* gnw = (const float*)d_in[1];
    const float* gnb = (const float*)d_in[2];
    const float* wq  = (const float*)d_in[3];
    const float* bq  = (const float*)d_in[4];
    const float* wk  = (const float*)d_in[5];
    const float* bk  = (const float*)d_in[6];
    const float* wv  = (const float*)d_in[7];
    const float* bv  = (const float*)d_in[8];
    const float* wp  = (const float*)d_in[9];
    const float* bp  = (const float*)d_in[10];
    float* out = (float*)d_out;

    const size_t NE = (size_t)NB * HW * CCH;          // 8388608 elements
    unsigned short* ws16 = (unsigned short*)d_ws;
    unsigned short* XT = ws16;                        // x_n transposed (b,s,c); reused as attn O
    unsigned short* Qb = ws16 + NE;
    unsigned short* Kb = ws16 + 2 * NE;
    unsigned short* Vt = ws16 + 3 * NE;               // V transposed: [b][c][s]
    unsigned short* Wb = ws16 + 4 * NE;               // 4 x 262144 bf16 weights
    float* stats = (float*)(ws16 + 4 * NE + 4 * 262144);

    // fold log2(e) into the attention scale so the kernel uses exp2 directly
    const float qscale = 0.08838834764831845f * 1.4426950408889634f;

    conv_w<<<dim3(256, 4), 256, 0, stream>>>(wq, wk, wv, wp, Wb);
    gn_stats<<<128, 256, 0, stream>>>(x, stats);
    gn_apply<<<dim3(16, 32, 4), 256, 0, stream>>>(x, gnw, gnb, stats, XT);

    // Q and K projections fused into one dispatch: z=0 -> Q (bias bq, *qscale), z=1 -> K (bias bk)
    gemm_nt<3><<<dim3(128, 4, 2), 256, 0, stream>>>(XT, 0, Wb, 262144, bq, qscale, bk, 0,
                                                    Qb, (long long)NE, 512);
    // V stored transposed: Vt[b][c][s] = Wv @ XT[b]^T
    gemm_nt<2><<<dim3(4, 32, 4), 256, 0, stream>>>(Wb + 2 * 262144, 0, XT, (long long)HW * 512, bv, 1.f,
                                                   nullptr, 0, Vt, (long long)CCH * HW, HW);

    unsigned short* Ob = XT;   // XT dead after QKV; reuse for attention output (b,s,c)
    attn_kern<<<dim3(256), dim3(512), 0, stream>>>(Qb, Kb, Vt, Ob);

    // out[b,o,s] = sum_c wp[o,c] * Ob[b,s,c] + bp[o] + x[b,o,s]
    gemm_nt<1><<<dim3(4, 32, 4), 256, 0, stream>>>(Wb + 3 * 262144, 0, Ob, (long long)HW * 512, bp, 1.f,
                                                   x, (long long)CCH * HW, out, (long long)CCH * HW, HW);
}

// Round 11
// 322.029 us; speedup vs baseline: 1.1503x; 1.0169x over previous
//
#include <hip/hip_runtime.h>
#include <math.h>

typedef __attribute__((ext_vector_type(8))) short short8;      // 8 bf16 (4 VGPRs) MFMA operand
typedef __attribute__((ext_vector_type(4))) float floatx4;     // 16x16 MFMA accumulator
typedef __attribute__((ext_vector_type(16))) float floatx16;   // 32x32 MFMA accumulator
typedef __attribute__((ext_vector_type(8))) unsigned short ushort8v;
typedef __attribute__((ext_vector_type(4))) unsigned short ushort4v;

#define HW 4096
#define CCH 512
#define NB 4
#define NH 4
#define HD 128

__device__ __forceinline__ unsigned short f2bf(float f) {
    union { float f; unsigned int u; } c; c.f = f;
    unsigned int u = c.u;
    u += 0x7FFFu + ((u >> 16) & 1u);   // round-to-nearest-even
    return (unsigned short)(u >> 16);
}

// async global->LDS DMA, 16B per lane. LDS dest = wave-uniform base + lane*16 (linear).
__device__ __forceinline__ void gload_lds16(const unsigned short* g, unsigned short* l) {
    __builtin_amdgcn_global_load_lds(
        (const __attribute__((address_space(1))) unsigned int*)g,
        (__attribute__((address_space(3))) unsigned int*)l, 16, 0, 0);
}

// ---------------- weights fp32 -> bf16 ----------------
__global__ void conv_w(const float* __restrict__ w0, const float* __restrict__ w1,
                       const float* __restrict__ w2, const float* __restrict__ w3,
                       unsigned short* __restrict__ dst) {
    const float* src = blockIdx.y == 0 ? w0 : blockIdx.y == 1 ? w1 : blockIdx.y == 2 ? w2 : w3;
    unsigned short* d = dst + (size_t)blockIdx.y * 262144;
    int i = blockIdx.x * 256 + threadIdx.x;          // float4 index, 65536 total
    float4 v = ((const float4*)src)[i];
    ushort4v o;
    o[0] = f2bf(v.x); o[1] = f2bf(v.y); o[2] = f2bf(v.z); o[3] = f2bf(v.w);
    ((ushort4v*)d)[i] = o;
}

// ---------------- GroupNorm stats: one block per (b, group) ----------------
__global__ void gn_stats(const float* __restrict__ x, float* __restrict__ stats) {
    int bg = blockIdx.x;                 // 0..127
    int b = bg >> 5, g = bg & 31;
    const float4* p = (const float4*)(x + ((size_t)b * CCH + g * 16) * HW);  // 16 ch * 4096 contiguous
    float s = 0.f, ss = 0.f;
    for (int i = threadIdx.x; i < 16384; i += 256) {
        float4 v = p[i];
        s  += v.x + v.y + v.z + v.w;
        ss += v.x * v.x + v.y * v.y + v.z * v.z + v.w * v.w;
    }
    #pragma unroll
    for (int off = 32; off > 0; off >>= 1) {
        s  += __shfl_down(s, off, 64);
        ss += __shfl_down(ss, off, 64);
    }
    __shared__ float sm[4], sm2[4];
    int wid = threadIdx.x >> 6;
    if ((threadIdx.x & 63) == 0) { sm[wid] = s; sm2[wid] = ss; }
    __syncthreads();
    if (threadIdx.x == 0) {
        float ts = sm[0] + sm[1] + sm[2] + sm[3];
        float tss = sm2[0] + sm2[1] + sm2[2] + sm2[3];
        float mean = ts * (1.f / 65536.f);
        float var = tss * (1.f / 65536.f) - mean * mean;
        stats[bg * 2] = mean;
        stats[bg * 2 + 1] = rsqrtf(var + 1e-5f);
    }
}

// ---------------- normalize + transpose -> XT[b, s, c] bf16 ----------------
__global__ void gn_apply(const float* __restrict__ x, const float* __restrict__ gnw,
                         const float* __restrict__ gnb, const float* __restrict__ stats,
                         unsigned short* __restrict__ xt) {
    int s = blockIdx.x * 256 + threadIdx.x;   // 0..4095
    int g = blockIdx.y, b = blockIdx.z;
    float mean = stats[(b * 32 + g) * 2];
    float rstd = stats[(b * 32 + g) * 2 + 1];
    const float* xb = x + ((size_t)b * CCH + g * 16) * HW + s;
    unsigned short outv[16];
    #pragma unroll
    for (int cl = 0; cl < 16; cl++) {
        int c = g * 16 + cl;
        float v = xb[(size_t)cl * HW];                       // lanes->consecutive s: coalesced
        v = (v - mean) * rstd * gnw[c] + gnb[c];
        outv[cl] = f2bf(v);
    }
    unsigned short* dst = xt + ((size_t)b * HW + s) * CCH + g * 16;   // 32B contiguous per thread
    *(ushort8v*)dst       = *(ushort8v*)&outv[0];
    *(ushort8v*)(dst + 8) = *(ushort8v*)&outv[8];
}

// ---------------- NT GEMM: C[m,n] = sum_k A[m,k] B[n,k], K=512 ----------------
// MODE 0: C bf16 [m,n], bias per-col n, *scale      (single projection)
// MODE 1: C fp32 [m,n], bias per-row m, + residual  (output projection + residual)
// MODE 2: V projection -> PACKED Vp layout: per (b,h), per kv-tile kt (64 t), slot order
//         slot = (t_local>>3)*128 + d  (t-granule-major), element e = t&7:
//         Vp[(b*NH+h)*524288 + kt*8192 + slot*8 + e].  This is EXACTLY the attn LDS slot
//         order -> DMA sources are contiguous 1KB and LDS reads are conflict-free.
// MODE 3: dual-launch over z: z=0 -> Q (bias, scale) row-major; z=1 -> K (resid-as-bias)
//         in PACKED Kp layout: slot = (d>>3)*64 + t_local, element e = d&7:
//         Kp[(b*NH+h)*524288 + kt*8192 + slot*8 + e].
//
// m97 structure: global_load_lds DMA staging into LINEAR [128][64]-ushort LDS tiles.
// Bank spread via XOR on the per-lane GLOBAL source granule with matching read-side XOR.
template <int MODE>
__global__ __launch_bounds__(256, 3) void gemm_nt(
    const unsigned short* __restrict__ A, long long aStride,
    const unsigned short* __restrict__ Bm, long long bStride,
    const float* __restrict__ bias, float scale,
    const float* __restrict__ resid, long long rStride,
    void* __restrict__ Cp, long long cStride, int ldc) {
    __shared__ __align__(16) unsigned short lA[128 * 64];
    __shared__ __align__(16) unsigned short lB[128 * 64];
    const int tid = threadIdx.x;
    const int lane = tid & 63;
    const int wid = tid >> 6;
    const int z = blockIdx.z;
    const unsigned short* Ab = A + (size_t)z * aStride + (size_t)blockIdx.x * 128 * 512;
    const unsigned short* Bb = Bm + (size_t)z * bStride + (size_t)blockIdx.y * 128 * 512;

    floatx4 acc[4][4];
    #pragma unroll
    for (int i = 0; i < 4; i++)
        #pragma unroll
        for (int j = 0; j < 4; j++) acc[i][j] = (floatx4)0.f;

    const int wm = (wid >> 1) * 64;
    const int wn = (wid & 1) * 64;
    const int l15 = lane & 15;
    const int l4 = lane >> 4;
    const int sxr = l15 & 7;              // read-side row-XOR key

    // DMA source offsets: slot (row, g_slot) <- global granule (row, g_slot ^ (row&7))
    size_t srcOff[4];
    int dstBase[4];
    #pragma unroll
    for (int n = 0; n < 4; n++) {
        int row = n * 32 + (tid >> 3);
        int g = tid & 7;
        srcOff[n] = (size_t)row * 512 + (size_t)((g ^ (row & 7)) << 3);
        dstBase[n] = (n * 256 + wid * 64) * 8;   // wave-uniform; HW adds lane*16B
    }

    #pragma unroll 1
    for (int t = 0; t < 8; t++) {
        int k0 = t * 64;
        #pragma unroll
        for (int n = 0; n < 4; n++) gload_lds16(&Ab[srcOff[n] + k0], lA + dstBase[n]);
        #pragma unroll
        for (int n = 0; n < 4; n++) gload_lds16(&Bb[srcOff[n] + k0], lB + dstBase[n]);
        __syncthreads();   // drains DMA (vmcnt) + publishes the tile
        #pragma unroll
        for (int kk = 0; kk < 2; kk++) {
            short8 af[4], bf[4];
            #pragma unroll
            for (int i = 0; i < 4; i++)
                af[i] = *(const short8*)&lA[(wm + i * 16 + l15) * 64 + (((kk * 4 + l4) ^ sxr) << 3)];
            #pragma unroll
            for (int j = 0; j < 4; j++)
                bf[j] = *(const short8*)&lB[(wn + j * 16 + l15) * 64 + (((kk * 4 + l4) ^ sxr) << 3)];
            #pragma unroll
            for (int i = 0; i < 4; i++)
                #pragma unroll
                for (int j = 0; j < 4; j++)
                    acc[i][j] = __builtin_amdgcn_mfma_f32_16x16x32_bf16(af[i], bf[j], acc[i][j], 0, 0, 0);
        }
        if (t < 7) __syncthreads();   // all reads done before next step's DMA overwrites
    }

    long long m0 = (long long)blockIdx.x * 128 + wm;
    long long n0 = (long long)blockIdx.y * 128 + wn;
    if (MODE == 3 && blockIdx.z == 1) {
        // K projection -> packed Kp: slot = (d>>3)*64 + (s&63), e = d&7, tile = s>>6
        unsigned short* C = (unsigned short*)Cp + (size_t)cStride;   // z==1 region
        #pragma unroll
        for (int i = 0; i < 4; i++)
            #pragma unroll
            for (int j = 0; j < 4; j++) {
                long long col = n0 + j * 16 + l15;                   // global channel c
                float bv = resid[col];                               // bk
                int hh = (int)(col >> 7);
                int d = (int)(col & 127);
                size_t dpart = (size_t)(d >> 3) * 512 + (size_t)(d & 7);   // (d>>3)*64 slots *8 + e
                #pragma unroll
                for (int r = 0; r < 4; r++) {
                    long long row = m0 + i * 16 + l4 * 4 + r;        // = b*4096 + s
                    int bb = (int)(row >> 12), s = (int)(row & 4095);
                    size_t addr = (size_t)(bb * NH + hh) * 524288
                                + (size_t)(s >> 6) * 8192 + dpart + (size_t)(s & 63) * 8;
                    C[addr] = f2bf(acc[i][j][r] + bv);
                }
            }
    } else if (MODE == 0 || MODE == 3) {
        unsigned short* C = (unsigned short*)Cp + (size_t)z * cStride;
        #pragma unroll
        for (int i = 0; i < 4; i++)
            #pragma unroll
            for (int j = 0; j < 4; j++) {
                long long col = n0 + j * 16 + l15;
                float bv = bias[col];
                #pragma unroll
                for (int r = 0; r < 4; r++) {
                    long long row = m0 + i * 16 + l4 * 4 + r;    // D: row=(lane>>4)*4+reg, col=lane&15
                    C[row * ldc + col] = f2bf((acc[i][j][r] + bv) * scale);
                }
            }
    } else if (MODE == 1) {
        float* C = (float*)Cp + (size_t)z * cStride;
        const float* R = resid + (size_t)z * rStride;
        #pragma unroll
        for (int i = 0; i < 4; i++)
            #pragma unroll
            for (int j = 0; j < 4; j++)
                #pragma unroll
                for (int r = 0; r < 4; r++) {
                    long long row = m0 + i * 16 + l4 * 4 + r;    // row = output channel o
                    long long col = n0 + j * 16 + l15;           // col = spatial s (coalesced)
                    C[row * ldc + col] = acc[i][j][r] + bias[row] + R[row * ldc + col];
                }
    } else {
        // MODE 2: V projection -> packed Vp: slot = ((s&63)>>3)*128 + d, e = s&7, tile = s>>6
        unsigned short* C = (unsigned short*)Cp;                 // base; batch folded into addr
        const int b = z;
        #pragma unroll
        for (int i = 0; i < 4; i++)
            #pragma unroll
            for (int j = 0; j < 4; j++)
                #pragma unroll
                for (int r = 0; r < 4; r++) {
                    long long row = m0 + i * 16 + l4 * 4 + r;    // global channel c
                    long long col = n0 + j * 16 + l15;           // spatial s
                    int hh = (int)(row >> 7);
                    int d = (int)(row & 127);
                    int s = (int)col;
                    size_t addr = (size_t)(b * NH + hh) * 524288
                                + (size_t)(s >> 6) * 8192
                                + (size_t)(((s & 63) >> 3) * 128 + d) * 8 + (size_t)(s & 7);
                    C[addr] = f2bf(acc[i][j][r] + bias[row]);
                }
    }
}

// ---------------- flash attention (no-max, 32x32 MFMA, packed-LDS, q-tile 256) ----------------
// One block per (q-tile 256, head, batch): 512 threads, 8 waves x 32 q-rows; grid 256 = 1/CU.
// K and V arrive PRE-PACKED in LDS slot order (written by the producer GEMMs):
//   K tile: slot = (d>>3)*64 + t   -> QK A-frag read = two contiguous 512B half-wave sweeps
//   V tile: slot = (t>>3)*128 + d  -> PV B-frag read = two contiguous 512B half-wave sweeps
// Bank math: byte addr = base + l31*16 -> dword residue l31*4 mod 32 tiles all 32 banks per
// 8 lanes -> ZERO conflicts (the old 256B-row-stride layout was 4-way degenerate, 8.4M
// conflict cycles). DMA sources are contiguous 1KB per instruction (no XOR gather).
// Pipeline, fragments, fused PV||QK cluster, MFMA rowsum: identical to the proven R9 kernel.
__global__ __launch_bounds__(512, 2) void attn_kern(
    const unsigned short* __restrict__ Qb, const unsigned short* __restrict__ Kp,
    const unsigned short* __restrict__ Vp, unsigned short* __restrict__ Ob) {
    __shared__ __align__(16) unsigned short lk0[8192], lk1[8192];   // K tiles (packed slots)
    __shared__ __align__(16) unsigned short lv0[8192], lv1[8192];   // V tiles (packed slots)
    const int tid = threadIdx.x;
    const int lane = tid & 63;
    const int w = tid >> 6;            // 0..7
    const int l31 = lane & 31;
    const int l1 = lane >> 5;
    const int bid = blockIdx.x;
    const int g = bid & 15;            // (b,h) group: all 16 q-tiles share bid%8 -> one XCD
    const int qt = bid >> 4;           // q-tile 0..15
    const int h = g & 3, b = g >> 2;
    const int q0 = qt * 256;
    const size_t headOff = (size_t)h * HD;
    const size_t batchRow = (size_t)b * HW;
    const unsigned short* KpB = Kp + (size_t)(b * NH + h) * 524288;   // packed K
    const unsigned short* VpB = Vp + (size_t)(b * NH + h) * 524288;   // packed V

    // DMA source offset within a tile: contiguous, wave w owns slots [w*128, w*128+128)
    const size_t dmaOff = (size_t)(w * 128 + lane) * 8;      // +n*512 per instruction (64 slots)
    const int ldsOff = w * 1024;                              // ushorts; +n*512 per instruction

    // Q fragments in registers: wave w owns q-rows [q0+w*32, q0+w*32+32)
    short8 qf[8];
    #pragma unroll
    for (int kd = 0; kd < 8; kd++)
        qf[kd] = *(const short8*)&Qb[(batchRow + q0 + w * 32 + l31) * 512
                                     + headOff + kd * 16 + l1 * 8];

    // all-ones B-fragment -> D[m][n] = rowsum(A[m][:])
    short8 onesf;
    #pragma unroll
    for (int e = 0; e < 8; e++) onesf[e] = (short)0x3F80;

    floatx16 acc_o[4];   // O[q][d]: col d = dj*32+l31, row q = (reg&3)+8*(reg>>2)+4*l1
    floatx16 acc_l;      // lsum[q]: same row pattern, every col identical
    acc_l = (floatx16)0.f;
    #pragma unroll
    for (int dj = 0; dj < 4; dj++) acc_o[dj] = (floatx16)0.f;

    // prologue: DMA K(0)->lk0, K(1)->lk1, V(0)->lv0; publish; QK(0); consumption barrier
    #pragma unroll
    for (int n = 0; n < 2; n++) gload_lds16(&KpB[dmaOff + n * 512], lk0 + ldsOff + n * 512);
    #pragma unroll
    for (int n = 0; n < 2; n++) gload_lds16(&KpB[dmaOff + 8192 + n * 512], lk1 + ldsOff + n * 512);
    #pragma unroll
    for (int n = 0; n < 2; n++) gload_lds16(&VpB[dmaOff + n * 512], lv0 + ldsOff + n * 512);
    __syncthreads();

    floatx16 sa0 = (floatx16)0.f, sa1 = (floatx16)0.f;
    #pragma unroll
    for (int kd = 0; kd < 8; kd++) {
        short8 kf0 = *(const short8*)&lk0[(kd * 2 + l1) * 512 + l31 * 8];
        short8 kf1 = *(const short8*)&lk0[(kd * 2 + l1) * 512 + 256 + l31 * 8];
        sa0 = __builtin_amdgcn_mfma_f32_32x32x16_bf16(kf0, qf[kd], sa0, 0, 0, 0);
        sa1 = __builtin_amdgcn_mfma_f32_32x32x16_bf16(kf1, qf[kd], sa1, 0, 0, 0);
    }
    __syncthreads();   // all waves done reading lk0 before iter 0's DMA K(2)->lk0

    unsigned short* lvCur = lv0;  unsigned short* lvNxt = lv1;
    unsigned short* kRead = lk1;  unsigned short* kWrite = lk0;

    #pragma unroll 1
    for (int kt = 0; kt < 63; kt++) {
        // issue async DMA: V(kt+1) -> lvNxt, K(kt+2) -> kWrite (targets consumed >=1 barrier
        // ago; kt=62's K(64) reads harmless in-workspace bytes and is never consumed)
        {
            size_t tv = (size_t)(kt + 1) * 8192;
            size_t tk = (size_t)(kt + 2) * 8192;
            #pragma unroll
            for (int n = 0; n < 2; n++) gload_lds16(&VpB[dmaOff + tv + n * 512], lvNxt + ldsOff + n * 512);
            #pragma unroll
            for (int n = 0; n < 2; n++) gload_lds16(&KpB[dmaOff + tk + n * 512], kWrite + ldsOff + n * 512);
        }

        // ---- pack(kt): p = exp2(S) in-register, cvt_pk pairs + permlane32_swap -> paf[0..3] ----
        short8 paf[4];
        #pragma unroll
        for (int r = 0; r < 16; r++) sa0[r] = __builtin_amdgcn_exp2f(sa0[r]);
        #pragma unroll
        for (int r = 0; r < 16; r++) sa1[r] = __builtin_amdgcn_exp2f(sa1[r]);
        #pragma unroll
        for (int tb = 0; tb < 2; tb++) {
            const floatx16& sa = tb ? sa1 : sa0;
            unsigned int wv[4][2];
            #pragma unroll
            for (int gg = 0; gg < 4; gg++) {
                asm("v_cvt_pk_bf16_f32 %0, %1, %2" : "=v"(wv[gg][0])
                    : "v"(sa[4 * gg + 0]), "v"(sa[4 * gg + 1]));
                asm("v_cvt_pk_bf16_f32 %0, %1, %2" : "=v"(wv[gg][1])
                    : "v"(sa[4 * gg + 2]), "v"(sa[4 * gg + 3]));
            }
            #pragma unroll
            for (int hh = 0; hh < 2; hh++) {
                unsigned int a0 = wv[2 * hh][0], b0 = wv[2 * hh + 1][0];
                unsigned int a1 = wv[2 * hh][1], b1 = wv[2 * hh + 1][1];
                asm("v_permlane32_swap_b32 %0, %1" : "+v"(a0), "+v"(b0));
                asm("v_permlane32_swap_b32 %0, %1" : "+v"(a1), "+v"(b1));
                union { unsigned int u[4]; short8 s8; } f;
                f.u[0] = a0; f.u[1] = a1; f.u[2] = b0; f.u[3] = b1;
                paf[2 * tb + hh] = f.s8;
            }
        }

        // ---- fused MFMA cluster: PV(kt) from lvCur  ||  QK(kt+1) from kRead ----
        sa0 = (floatx16)0.f; sa1 = (floatx16)0.f;
        __builtin_amdgcn_s_setprio(1);
        #pragma unroll
        for (int u = 0; u < 4; u++) {
            #pragma unroll
            for (int q2 = 0; q2 < 2; q2++) {
                int kd = u * 2 + q2;
                short8 kf0 = *(const short8*)&kRead[(kd * 2 + l1) * 512 + l31 * 8];
                short8 kf1 = *(const short8*)&kRead[(kd * 2 + l1) * 512 + 256 + l31 * 8];
                sa0 = __builtin_amdgcn_mfma_f32_32x32x16_bf16(kf0, qf[kd], sa0, 0, 0, 0);
                sa1 = __builtin_amdgcn_mfma_f32_32x32x16_bf16(kf1, qf[kd], sa1, 0, 0, 0);
            }
            acc_l = __builtin_amdgcn_mfma_f32_32x32x16_bf16(paf[u], onesf, acc_l, 0, 0, 0);
            #pragma unroll
            for (int dj = 0; dj < 4; dj++) {
                short8 vv = *(const short8*)&lvCur[(u * 2 + l1) * 1024 + dj * 256 + l31 * 8];
                acc_o[dj] = __builtin_amdgcn_mfma_f32_32x32x16_bf16(paf[u], vv, acc_o[dj], 0, 0, 0);
            }
        }
        __builtin_amdgcn_s_setprio(0);

        __syncthreads();   // drains this wave's DMA (vmcnt) + publishes tiles V(kt+1), K(kt+2)
        unsigned short* t;
        t = lvCur; lvCur = lvNxt; lvNxt = t;
        t = kRead; kRead = kWrite; kWrite = t;
    }

    // ---- tail kt=63: pack + PV only ----
    {
        short8 paf[4];
        #pragma unroll
        for (int r = 0; r < 16; r++) sa0[r] = __builtin_amdgcn_exp2f(sa0[r]);
        #pragma unroll
        for (int r = 0; r < 16; r++) sa1[r] = __builtin_amdgcn_exp2f(sa1[r]);
        #pragma unroll
        for (int tb = 0; tb < 2; tb++) {
            const floatx16& sa = tb ? sa1 : sa0;
            unsigned int wv[4][2];
            #pragma unroll
            for (int gg = 0; gg < 4; gg++) {
                asm("v_cvt_pk_bf16_f32 %0, %1, %2" : "=v"(wv[gg][0])
                    : "v"(sa[4 * gg + 0]), "v"(sa[4 * gg + 1]));
                asm("v_cvt_pk_bf16_f32 %0, %1, %2" : "=v"(wv[gg][1])
                    : "v"(sa[4 * gg + 2]), "v"(sa[4 * gg + 3]));
            }
            #pragma unroll
            for (int hh = 0; hh < 2; hh++) {
                unsigned int a0 = wv[2 * hh][0], b0 = wv[2 * hh + 1][0];
                unsigned int a1 = wv[2 * hh][1], b1 = wv[2 * hh + 1][1];
                asm("v_permlane32_swap_b32 %0, %1" : "+v"(a0), "+v"(b0));
                asm("v_permlane32_swap_b32 %0, %1" : "+v"(a1), "+v"(b1));
                union { unsigned int u[4]; short8 s8; } f;
                f.u[0] = a0; f.u[1] = a1; f.u[2] = b0; f.u[3] = b1;
                paf[2 * tb + hh] = f.s8;
            }
        }
        __builtin_amdgcn_s_setprio(1);
        #pragma unroll
        for (int u = 0; u < 4; u++) {
            acc_l = __builtin_amdgcn_mfma_f32_32x32x16_bf16(paf[u], onesf, acc_l, 0, 0, 0);
            #pragma unroll
            for (int dj = 0; dj < 4; dj++) {
                short8 vv = *(const short8*)&lvCur[(u * 2 + l1) * 1024 + dj * 256 + l31 * 8];
                acc_o[dj] = __builtin_amdgcn_mfma_f32_32x32x16_bf16(paf[u], vv, acc_o[dj], 0, 0, 0);
            }
        }
        __builtin_amdgcn_s_setprio(0);
    }

    // epilogue: acc_l[reg] holds lsum for exactly the q-row acc_o[.][reg] holds
    #pragma unroll
    for (int gg = 0; gg < 4; gg++)
        #pragma unroll
        for (int p = 0; p < 4; p++) {
            int reg = 4 * gg + p;
            float rl = 1.f / acc_l[reg];
            int qr = p + 8 * gg + 4 * l1;
            size_t row = batchRow + q0 + w * 32 + qr;
            #pragma unroll
            for (int dj = 0; dj < 4; dj++)
                Ob[row * 512 + headOff + dj * 32 + l31] = f2bf(acc_o[dj][reg] * rl);
        }
}

extern "C" void kernel_launch(void* const* d_in, const int* in_sizes, int n_in,
                              void* d_out, int out_size, void* d_ws, size_t ws_size,
                              hipStream_t stream) {
    const float* x   = (const float*)d_in[0];
    const float* gnw = (const float*)d_in[1];
    const float* gnb = (const float*)d_in[2];
    const float* wq  = (const float*)d_in[3];
    const float* bq  = (const float*)d_in[4];
    const float* wk  = (const float*)d_in[5];
    const float* bk  = (const float*)d_in[6];
    const float* wv  = (const float*)d_in[7];
    const float* bv  = (const float*)d_in[8];
    const float* wp  = (const float*)d_in[9];
    const float* bp  = (const float*)d_in[10];
    float* out = (float*)d_out;

    const size_t NE = (size_t)NB * HW * CCH;          // 8388608 elements
    unsigned short* ws16 = (unsigned short*)d_ws;
    unsigned short* XT = ws16;                        // x_n transposed (b,s,c); reused as attn O
    unsigned short* Qb = ws16 + NE;
    unsigned short* Kb = ws16 + 2 * NE;               // K packed per (b,h) in attn LDS slot order
    unsigned short* Vt = ws16 + 3 * NE;               // V packed per (b,h) in attn LDS slot order
    unsigned short* Wb = ws16 + 4 * NE;               // 4 x 262144 bf16 weights
    float* stats = (float*)(ws16 + 4 * NE + 4 * 262144);

    // fold log2(e) into the attention scale so the kernel uses exp2 directly
    const float qscale = 0.08838834764831845f * 1.4426950408889634f;

    conv_w<<<dim3(256, 4), 256, 0, stream>>>(wq, wk, wv, wp, Wb);
    gn_stats<<<128, 256, 0, stream>>>(x, stats);
    gn_apply<<<dim3(16, 32, 4), 256, 0, stream>>>(x, gnw, gnb, stats, XT);

    // Q and K projections fused into one dispatch: z=0 -> Q (bias bq, *qscale), z=1 -> K packed
    gemm_nt<3><<<dim3(128, 4, 2), 256, 0, stream>>>(XT, 0, Wb, 262144, bq, qscale, bk, 0,
                                                    Qb, (long long)NE, 512);
    // V projection -> packed Vp layout
    gemm_nt<2><<<dim3(4, 32, 4), 256, 0, stream>>>(Wb + 2 * 262144, 0, XT, (long long)HW * 512, bv, 1.f,
                                                   nullptr, 0, Vt, 0, HW);

    unsigned short* Ob = XT;   // XT dead after QKV; reuse for attention output (b,s,c)
    attn_kern<<<dim3(256), dim3(512), 0, stream>>>(Qb, Kb, Vt, Ob);

    // out[b,o,s] = sum_c wp[o,c] * Ob[b,s,c] + bp[o] + x[b,o,s]
    gemm_nt<1><<<dim3(4, 32, 4), 256, 0, stream>>>(Wb + 3 * 262144, 0, Ob, (long long)HW * 512, bp, 1.f,
                                                   x, (long long)CCH * HW, out, (long long)CCH * HW, HW);
}

// Round 12
// 319.797 us; speedup vs baseline: 1.1584x; 1.0070x over previous
//
#include <hip/hip_runtime.h>
#include <math.h>

typedef __attribute__((ext_vector_type(8))) short short8;      // 8 bf16 (4 VGPRs) MFMA operand
typedef __attribute__((ext_vector_type(4))) float floatx4;     // 16x16 MFMA accumulator
typedef __attribute__((ext_vector_type(16))) float floatx16;   // 32x32 MFMA accumulator
typedef __attribute__((ext_vector_type(8))) unsigned short ushort8v;
typedef __attribute__((ext_vector_type(4))) unsigned short ushort4v;

#define HW 4096
#define CCH 512
#define NB 4
#define NH 4
#define HD 128

__device__ __forceinline__ unsigned short f2bf(float f) {
    union { float f; unsigned int u; } c; c.f = f;
    unsigned int u = c.u;
    u += 0x7FFFu + ((u >> 16) & 1u);   // round-to-nearest-even
    return (unsigned short)(u >> 16);
}

// async global->LDS DMA, 16B per lane. LDS dest = wave-uniform base + lane*16 (linear).
__device__ __forceinline__ void gload_lds16(const unsigned short* g, unsigned short* l) {
    __builtin_amdgcn_global_load_lds(
        (const __attribute__((address_space(1))) unsigned int*)g,
        (__attribute__((address_space(3))) unsigned int*)l, 16, 0, 0);
}

__device__ __forceinline__ float sum16(const floatx16& s) {
    return ((((s[0] + s[1]) + (s[2] + s[3])) + ((s[4] + s[5]) + (s[6] + s[7])))
          + (((s[8] + s[9]) + (s[10] + s[11])) + ((s[12] + s[13]) + (s[14] + s[15]))));
}

// ---------------- weights fp32 -> bf16 ----------------
__global__ void conv_w(const float* __restrict__ w0, const float* __restrict__ w1,
                       const float* __restrict__ w2, const float* __restrict__ w3,
                       unsigned short* __restrict__ dst) {
    const float* src = blockIdx.y == 0 ? w0 : blockIdx.y == 1 ? w1 : blockIdx.y == 2 ? w2 : w3;
    unsigned short* d = dst + (size_t)blockIdx.y * 262144;
    int i = blockIdx.x * 256 + threadIdx.x;          // float4 index, 65536 total
    float4 v = ((const float4*)src)[i];
    ushort4v o;
    o[0] = f2bf(v.x); o[1] = f2bf(v.y); o[2] = f2bf(v.z); o[3] = f2bf(v.w);
    ((ushort4v*)d)[i] = o;
}

// ---------------- GroupNorm stats: one block per (b, group) ----------------
__global__ void gn_stats(const float* __restrict__ x, float* __restrict__ stats) {
    int bg = blockIdx.x;                 // 0..127
    int b = bg >> 5, g = bg & 31;
    const float4* p = (const float4*)(x + ((size_t)b * CCH + g * 16) * HW);  // 16 ch * 4096 contiguous
    float s = 0.f, ss = 0.f;
    for (int i = threadIdx.x; i < 16384; i += 256) {
        float4 v = p[i];
        s  += v.x + v.y + v.z + v.w;
        ss += v.x * v.x + v.y * v.y + v.z * v.z + v.w * v.w;
    }
    #pragma unroll
    for (int off = 32; off > 0; off >>= 1) {
        s  += __shfl_down(s, off, 64);
        ss += __shfl_down(ss, off, 64);
    }
    __shared__ float sm[4], sm2[4];
    int wid = threadIdx.x >> 6;
    if ((threadIdx.x & 63) == 0) { sm[wid] = s; sm2[wid] = ss; }
    __syncthreads();
    if (threadIdx.x == 0) {
        float ts = sm[0] + sm[1] + sm[2] + sm[3];
        float tss = sm2[0] + sm2[1] + sm2[2] + sm2[3];
        float mean = ts * (1.f / 65536.f);
        float var = tss * (1.f / 65536.f) - mean * mean;
        stats[bg * 2] = mean;
        stats[bg * 2 + 1] = rsqrtf(var + 1e-5f);
    }
}

// ---------------- normalize + transpose -> XT[b, s, c] bf16 ----------------
__global__ void gn_apply(const float* __restrict__ x, const float* __restrict__ gnw,
                         const float* __restrict__ gnb, const float* __restrict__ stats,
                         unsigned short* __restrict__ xt) {
    int s = blockIdx.x * 256 + threadIdx.x;   // 0..4095
    int g = blockIdx.y, b = blockIdx.z;
    float mean = stats[(b * 32 + g) * 2];
    float rstd = stats[(b * 32 + g) * 2 + 1];
    const float* xb = x + ((size_t)b * CCH + g * 16) * HW + s;
    unsigned short outv[16];
    #pragma unroll
    for (int cl = 0; cl < 16; cl++) {
        int c = g * 16 + cl;
        float v = xb[(size_t)cl * HW];                       // lanes->consecutive s: coalesced
        v = (v - mean) * rstd * gnw[c] + gnb[c];
        outv[cl] = f2bf(v);
    }
    unsigned short* dst = xt + ((size_t)b * HW + s) * CCH + g * 16;   // 32B contiguous per thread
    *(ushort8v*)dst       = *(ushort8v*)&outv[0];
    *(ushort8v*)(dst + 8) = *(ushort8v*)&outv[8];
}

// ---------------- NT GEMM: C[m,n] = sum_k A[m,k] B[n,k], K=512 ----------------
// MODE 0: C bf16 [m,n], bias per-col n, *scale      (single projection)
// MODE 1: C fp32 [m,n], bias per-row m, + residual  (output projection + residual)
// MODE 2: V projection -> PACKED Vp layout: per (b,h), per kv-tile kt (64 t), slot order
//         slot = (t_local>>3)*128 + d, element e = t&7 -> attn LDS slot order.
// MODE 3: dual-launch over z: z=0 -> Q (bias, scale) row-major; z=1 -> K (resid-as-bias)
//         in PACKED Kp layout: slot = (d>>3)*64 + t_local, element e = d&7.
//
// m97 structure: global_load_lds DMA staging into LINEAR [128][64]-ushort LDS tiles.
// Bank spread via XOR on the per-lane GLOBAL source granule with matching read-side XOR.
template <int MODE>
__global__ __launch_bounds__(256, 3) void gemm_nt(
    const unsigned short* __restrict__ A, long long aStride,
    const unsigned short* __restrict__ Bm, long long bStride,
    const float* __restrict__ bias, float scale,
    const float* __restrict__ resid, long long rStride,
    void* __restrict__ Cp, long long cStride, int ldc) {
    __shared__ __align__(16) unsigned short lA[128 * 64];
    __shared__ __align__(16) unsigned short lB[128 * 64];
    const int tid = threadIdx.x;
    const int lane = tid & 63;
    const int wid = tid >> 6;
    const int z = blockIdx.z;
    const unsigned short* Ab = A + (size_t)z * aStride + (size_t)blockIdx.x * 128 * 512;
    const unsigned short* Bb = Bm + (size_t)z * bStride + (size_t)blockIdx.y * 128 * 512;

    floatx4 acc[4][4];
    #pragma unroll
    for (int i = 0; i < 4; i++)
        #pragma unroll
        for (int j = 0; j < 4; j++) acc[i][j] = (floatx4)0.f;

    const int wm = (wid >> 1) * 64;
    const int wn = (wid & 1) * 64;
    const int l15 = lane & 15;
    const int l4 = lane >> 4;
    const int sxr = l15 & 7;              // read-side row-XOR key

    // DMA source offsets: slot (row, g_slot) <- global granule (row, g_slot ^ (row&7))
    size_t srcOff[4];
    int dstBase[4];
    #pragma unroll
    for (int n = 0; n < 4; n++) {
        int row = n * 32 + (tid >> 3);
        int g = tid & 7;
        srcOff[n] = (size_t)row * 512 + (size_t)((g ^ (row & 7)) << 3);
        dstBase[n] = (n * 256 + wid * 64) * 8;   // wave-uniform; HW adds lane*16B
    }

    #pragma unroll 1
    for (int t = 0; t < 8; t++) {
        int k0 = t * 64;
        #pragma unroll
        for (int n = 0; n < 4; n++) gload_lds16(&Ab[srcOff[n] + k0], lA + dstBase[n]);
        #pragma unroll
        for (int n = 0; n < 4; n++) gload_lds16(&Bb[srcOff[n] + k0], lB + dstBase[n]);
        __syncthreads();   // drains DMA (vmcnt) + publishes the tile
        #pragma unroll
        for (int kk = 0; kk < 2; kk++) {
            short8 af[4], bf[4];
            #pragma unroll
            for (int i = 0; i < 4; i++)
                af[i] = *(const short8*)&lA[(wm + i * 16 + l15) * 64 + (((kk * 4 + l4) ^ sxr) << 3)];
            #pragma unroll
            for (int j = 0; j < 4; j++)
                bf[j] = *(const short8*)&lB[(wn + j * 16 + l15) * 64 + (((kk * 4 + l4) ^ sxr) << 3)];
            #pragma unroll
            for (int i = 0; i < 4; i++)
                #pragma unroll
                for (int j = 0; j < 4; j++)
                    acc[i][j] = __builtin_amdgcn_mfma_f32_16x16x32_bf16(af[i], bf[j], acc[i][j], 0, 0, 0);
        }
        if (t < 7) __syncthreads();   // all reads done before next step's DMA overwrites
    }

    long long m0 = (long long)blockIdx.x * 128 + wm;
    long long n0 = (long long)blockIdx.y * 128 + wn;
    if (MODE == 3 && blockIdx.z == 1) {
        // K projection -> packed Kp: slot = (d>>3)*64 + (s&63), e = d&7, tile = s>>6
        unsigned short* C = (unsigned short*)Cp + (size_t)cStride;   // z==1 region
        #pragma unroll
        for (int i = 0; i < 4; i++)
            #pragma unroll
            for (int j = 0; j < 4; j++) {
                long long col = n0 + j * 16 + l15;                   // global channel c
                float bv = resid[col];                               // bk
                int hh = (int)(col >> 7);
                int d = (int)(col & 127);
                size_t dpart = (size_t)(d >> 3) * 512 + (size_t)(d & 7);   // (d>>3)*64 slots *8 + e
                #pragma unroll
                for (int r = 0; r < 4; r++) {
                    long long row = m0 + i * 16 + l4 * 4 + r;        // = b*4096 + s
                    int bb = (int)(row >> 12), s = (int)(row & 4095);
                    size_t addr = (size_t)(bb * NH + hh) * 524288
                                + (size_t)(s >> 6) * 8192 + dpart + (size_t)(s & 63) * 8;
                    C[addr] = f2bf(acc[i][j][r] + bv);
                }
            }
    } else if (MODE == 0 || MODE == 3) {
        unsigned short* C = (unsigned short*)Cp + (size_t)z * cStride;
        #pragma unroll
        for (int i = 0; i < 4; i++)
            #pragma unroll
            for (int j = 0; j < 4; j++) {
                long long col = n0 + j * 16 + l15;
                float bv = bias[col];
                #pragma unroll
                for (int r = 0; r < 4; r++) {
                    long long row = m0 + i * 16 + l4 * 4 + r;    // D: row=(lane>>4)*4+reg, col=lane&15
                    C[row * ldc + col] = f2bf((acc[i][j][r] + bv) * scale);
                }
            }
    } else if (MODE == 1) {
        float* C = (float*)Cp + (size_t)z * cStride;
        const float* R = resid + (size_t)z * rStride;
        #pragma unroll
        for (int i = 0; i < 4; i++)
            #pragma unroll
            for (int j = 0; j < 4; j++)
                #pragma unroll
                for (int r = 0; r < 4; r++) {
                    long long row = m0 + i * 16 + l4 * 4 + r;    // row = output channel o
                    long long col = n0 + j * 16 + l15;           // col = spatial s (coalesced)
                    C[row * ldc + col] = acc[i][j][r] + bias[row] + R[row * ldc + col];
                }
    } else {
        // MODE 2: V projection -> packed Vp: slot = ((s&63)>>3)*128 + d, e = s&7, tile = s>>6
        unsigned short* C = (unsigned short*)Cp;                 // base; batch folded into addr
        const int b = z;
        #pragma unroll
        for (int i = 0; i < 4; i++)
            #pragma unroll
            for (int j = 0; j < 4; j++)
                #pragma unroll
                for (int r = 0; r < 4; r++) {
                    long long row = m0 + i * 16 + l4 * 4 + r;    // global channel c
                    long long col = n0 + j * 16 + l15;           // spatial s
                    int hh = (int)(row >> 7);
                    int d = (int)(row & 127);
                    int s = (int)col;
                    size_t addr = (size_t)(b * NH + hh) * 524288
                                + (size_t)(s >> 6) * 8192
                                + (size_t)(((s & 63) >> 3) * 128 + d) * 8 + (size_t)(s & 7);
                    C[addr] = f2bf(acc[i][j][r] + bias[row]);
                }
    }
}

// ---------------- flash attention (no-max, 32x32 MFMA, packed-LDS, q-256, parity-S) ----------------
// One block per (q-tile 256, head, batch): 512 threads, 8 waves x 32 q-rows; grid 256 = 1/CU.
// K/V pre-packed in LDS slot order (producer GEMMs) -> conflict-free b128 reads (R11: 0 conflicts).
//
// PARITY-S PIPELINE (this round): S double-buffered by kt parity (saA/saB). Per step:
//   DMA(V kt+1, K kt+2) -> QK(kt+1) writes saNEW -> pack(kt) reads saOLD -> PV(kt) -> barrier.
// pack has NO WAR hazard against QK (different S buffers) -> its ~100 VALU ops issue in the
// 16-MFMA QK shadow instead of draining the matrix pipe (the ~2300 idle cyc/kt of R11).
// R6 tried this via lambdas and spilled (VGPR 128 + scratch); straight macro code here.
// Peak regs: acc_o 64 + saA/saB 64 + qf 32 + paf 16 + addr ~= 195 < 256 cap (2 waves/SIMD).
// WRITE_SIZE must stay 16384 (spill tripwire).
//
// lsum OFF the MFMA pipe (verified correct in R6/R7): VALU sum16 over exp2 outputs inside pack
// (free in the QK shadow), finalize via permlane32_swap + __shfl. Saves 4 MFMA/wave/kt (11%).
__global__ __launch_bounds__(512, 2) void attn_kern(
    const unsigned short* __restrict__ Qb, const unsigned short* __restrict__ Kp,
    const unsigned short* __restrict__ Vp, unsigned short* __restrict__ Ob) {
    __shared__ __align__(16) unsigned short lk0[8192], lk1[8192];   // K tiles (packed slots)
    __shared__ __align__(16) unsigned short lv0[8192], lv1[8192];   // V tiles (packed slots)
    const int tid = threadIdx.x;
    const int lane = tid & 63;
    const int w = tid >> 6;            // 0..7
    const int l31 = lane & 31;
    const int l1 = lane >> 5;
    const int bid = blockIdx.x;
    const int g = bid & 15;            // (b,h) group: all 16 q-tiles share bid%8 -> one XCD
    const int qt = bid >> 4;           // q-tile 0..15
    const int h = g & 3, b = g >> 2;
    const int q0 = qt * 256;
    const size_t headOff = (size_t)h * HD;
    const size_t batchRow = (size_t)b * HW;
    const unsigned short* KpB = Kp + (size_t)(b * NH + h) * 524288;   // packed K
    const unsigned short* VpB = Vp + (size_t)(b * NH + h) * 524288;   // packed V

    // DMA source offset within a tile: contiguous, wave w owns slots [w*128, w*128+128)
    const size_t dmaOff = (size_t)(w * 128 + lane) * 8;      // +n*512 per instruction (64 slots)
    const int ldsOff = w * 1024;                              // ushorts; +n*512 per instruction

    // Q fragments in registers: wave w owns q-rows [q0+w*32, q0+w*32+32)
    short8 qf[8];
    #pragma unroll
    for (int kd = 0; kd < 8; kd++)
        qf[kd] = *(const short8*)&Qb[(batchRow + q0 + w * 32 + l31) * 512
                                     + headOff + kd * 16 + l1 * 8];

    floatx16 acc_o[4];   // O[q][d]: col d = dj*32+l31, row q = (reg&3)+8*(reg>>2)+4*l1
    #pragma unroll
    for (int dj = 0; dj < 4; dj++) acc_o[dj] = (floatx16)0.f;
    float lsum_part = 0.f;   // per-lane partial rowsum for col q=l31 over this lane's t-rows

    // prologue: DMA K(0)->lk0, K(1)->lk1, V(0)->lv0; publish; QK(0)->saA; consumption barrier
    #pragma unroll
    for (int n = 0; n < 2; n++) gload_lds16(&KpB[dmaOff + n * 512], lk0 + ldsOff + n * 512);
    #pragma unroll
    for (int n = 0; n < 2; n++) gload_lds16(&KpB[dmaOff + 8192 + n * 512], lk1 + ldsOff + n * 512);
    #pragma unroll
    for (int n = 0; n < 2; n++) gload_lds16(&VpB[dmaOff + n * 512], lv0 + ldsOff + n * 512);
    __syncthreads();

    floatx16 saA0 = (floatx16)0.f, saA1 = (floatx16)0.f;
    floatx16 saB0, saB1;
    #pragma unroll
    for (int kd = 0; kd < 8; kd++) {
        short8 kf0 = *(const short8*)&lk0[(kd * 2 + l1) * 512 + l31 * 8];
        short8 kf1 = *(const short8*)&lk0[(kd * 2 + l1) * 512 + 256 + l31 * 8];
        saA0 = __builtin_amdgcn_mfma_f32_32x32x16_bf16(kf0, qf[kd], saA0, 0, 0, 0);
        saA1 = __builtin_amdgcn_mfma_f32_32x32x16_bf16(kf1, qf[kd], saA1, 0, 0, 0);
    }
    __syncthreads();   // all waves done reading lk0 before step(0)'s DMA K(2)->lk0

    unsigned short* lvCur = lv0;  unsigned short* lvNxt = lv1;
    unsigned short* kRead = lk1;  unsigned short* kWrite = lk0;

// pack(S0,S1): exp2 in place, lsum add-tree, cvt_pk + permlane32_swap -> paf[0..3]
#define ATTN_PACK(S0, S1)                                                                 \
    short8 paf[4];                                                                        \
    {                                                                                     \
        _Pragma("unroll") for (int r = 0; r < 16; r++) S0[r] = __builtin_amdgcn_exp2f(S0[r]); \
        _Pragma("unroll") for (int r = 0; r < 16; r++) S1[r] = __builtin_amdgcn_exp2f(S1[r]); \
        lsum_part += sum16(S0) + sum16(S1);                                               \
        _Pragma("unroll") for (int tb = 0; tb < 2; tb++) {                                \
            const floatx16& sa_ = tb ? S1 : S0;                                           \
            unsigned int wv[4][2];                                                        \
            _Pragma("unroll") for (int gg = 0; gg < 4; gg++) {                            \
                asm("v_cvt_pk_bf16_f32 %0, %1, %2" : "=v"(wv[gg][0])                      \
                    : "v"(sa_[4 * gg + 0]), "v"(sa_[4 * gg + 1]));                        \
                asm("v_cvt_pk_bf16_f32 %0, %1, %2" : "=v"(wv[gg][1])                      \
                    : "v"(sa_[4 * gg + 2]), "v"(sa_[4 * gg + 3]));                        \
            }                                                                             \
            _Pragma("unroll") for (int hh = 0; hh < 2; hh++) {                            \
                unsigned int a0 = wv[2 * hh][0], b0 = wv[2 * hh + 1][0];                  \
                unsigned int a1 = wv[2 * hh][1], b1 = wv[2 * hh + 1][1];                  \
                asm("v_permlane32_swap_b32 %0, %1" : "+v"(a0), "+v"(b0));                 \
                asm("v_permlane32_swap_b32 %0, %1" : "+v"(a1), "+v"(b1));                 \
                union { unsigned int u[4]; short8 s8; } f_;                               \
                f_.u[0] = a0; f_.u[1] = a1; f_.u[2] = b0; f_.u[3] = b1;                   \
                paf[2 * tb + hh] = f_.s8;                                                 \
            }                                                                             \
        }                                                                                 \
    }

// PV: 16 MFMA from lvCur (conflict-free packed reads)
#define ATTN_PV                                                                           \
    _Pragma("unroll") for (int u = 0; u < 4; u++) {                                       \
        _Pragma("unroll") for (int dj = 0; dj < 4; dj++) {                                \
            short8 vv = *(const short8*)&lvCur[(u * 2 + l1) * 1024 + dj * 256 + l31 * 8]; \
            acc_o[dj] = __builtin_amdgcn_mfma_f32_32x32x16_bf16(paf[u], vv, acc_o[dj], 0, 0, 0); \
        }                                                                                 \
    }

// one pipeline step: DMA -> QK(KT+1)->saNEW -> pack(KT) from saOLD (in QK shadow) -> PV(KT)
#define ATTN_STEP(KT, SO0, SO1, SN0, SN1)                                                 \
    {                                                                                     \
        size_t tv = (size_t)((KT) + 1) * 8192;                                            \
        size_t tk = (size_t)((KT) + 2) * 8192;                                            \
        _Pragma("unroll") for (int n = 0; n < 2; n++)                                     \
            gload_lds16(&VpB[dmaOff + tv + n * 512], lvNxt + ldsOff + n * 512);           \
        _Pragma("unroll") for (int n = 0; n < 2; n++)                                     \
            gload_lds16(&KpB[dmaOff + tk + n * 512], kWrite + ldsOff + n * 512);          \
        SN0 = (floatx16)0.f; SN1 = (floatx16)0.f;                                         \
        __builtin_amdgcn_s_setprio(1);                                                    \
        _Pragma("unroll") for (int kd = 0; kd < 8; kd++) {                                \
            short8 kf0 = *(const short8*)&kRead[(kd * 2 + l1) * 512 + l31 * 8];           \
            short8 kf1 = *(const short8*)&kRead[(kd * 2 + l1) * 512 + 256 + l31 * 8];     \
            SN0 = __builtin_amdgcn_mfma_f32_32x32x16_bf16(kf0, qf[kd], SN0, 0, 0, 0);     \
            SN1 = __builtin_amdgcn_mfma_f32_32x32x16_bf16(kf1, qf[kd], SN1, 0, 0, 0);     \
        }                                                                                 \
        ATTN_PACK(SO0, SO1)                                                               \
        ATTN_PV                                                                           \
        __builtin_amdgcn_s_setprio(0);                                                    \
        __syncthreads();                                                                  \
        { unsigned short* t_ = lvCur; lvCur = lvNxt; lvNxt = t_;                          \
          t_ = kRead; kRead = kWrite; kWrite = t_; }                                      \
    }

    // steps kt=0..61 (parity pairs), then kt=62; step(62)'s K(64) prefetch reads in-workspace
    // bytes past this group's Kp (next group / Vp start) and is never consumed.
    #pragma unroll 1
    for (int it = 0; it < 31; it++) {
        ATTN_STEP(2 * it,     saA0, saA1, saB0, saB1);
        ATTN_STEP(2 * it + 1, saB0, saB1, saA0, saA1);
    }
    ATTN_STEP(62, saA0, saA1, saB0, saB1);

    // tail kt=63: pack(saB) + PV only (lvCur holds V(63), published by step(62)'s barrier)
    {
        ATTN_PACK(saB0, saB1)
        __builtin_amdgcn_s_setprio(1);
        ATTN_PV
        __builtin_amdgcn_s_setprio(0);
    }
#undef ATTN_STEP
#undef ATTN_PV
#undef ATTN_PACK

    // lsum finalize: own-half + partner-half -> lsum[q=l31] in every lane (R6/R7-verified)
    float tot;
    {
        union { float f; unsigned int u; } ua, ub;
        ua.f = lsum_part; ub.f = lsum_part;
        asm("v_permlane32_swap_b32 %0, %1" : "+v"(ua.u), "+v"(ub.u));
        tot = ua.f + ub.f;
    }

    // epilogue: acc_o[dj][reg] is q-row qr = (reg&3)+8*(reg>>2)+4*l1; lsum[qr] lives in lane qr
    #pragma unroll
    for (int gg = 0; gg < 4; gg++)
        #pragma unroll
        for (int p = 0; p < 4; p++) {
            int reg = 4 * gg + p;
            int qr = p + 8 * gg + 4 * l1;
            float rl = 1.f / __shfl(tot, qr, 64);
            size_t row = batchRow + q0 + w * 32 + qr;
            #pragma unroll
            for (int dj = 0; dj < 4; dj++)
                Ob[row * 512 + headOff + dj * 32 + l31] = f2bf(acc_o[dj][reg] * rl);
        }
}

extern "C" void kernel_launch(void* const* d_in, const int* in_sizes, int n_in,
                              void* d_out, int out_size, void* d_ws, size_t ws_size,
                              hipStream_t stream) {
    const float* x   = (const float*)d_in[0];
    const float* gnw = (const float*)d_in[1];
    const float* gnb = (const float*)d_in[2];
    const float* wq  = (const float*)d_in[3];
    const float* bq  = (const float*)d_in[4];
    const float* wk  = (const float*)d_in[5];
    const float* bk  = (const float*)d_in[6];
    const float* wv  = (const float*)d_in[7];
    const float* bv  = (const float*)d_in[8];
    const float* wp  = (const float*)d_in[9];
    const float* bp  = (const float*)d_in[10];
    float* out = (float*)d_out;

    const size_t NE = (size_t)NB * HW * CCH;          // 8388608 elements
    unsigned short* ws16 = (unsigned short*)d_ws;
    unsigned short* XT = ws16;                        // x_n transposed (b,s,c); reused as attn O
    unsigned short* Qb = ws16 + NE;
    unsigned short* Kb = ws16 + 2 * NE;               // K packed per (b,h) in attn LDS slot order
    unsigned short* Vt = ws16 + 3 * NE;               // V packed per (b,h) in attn LDS slot order
    unsigned short* Wb = ws16 + 4 * NE;               // 4 x 262144 bf16 weights
    float* stats = (float*)(ws16 + 4 * NE + 4 * 262144);

    // fold log2(e) into the attention scale so the kernel uses exp2 directly
    const float qscale = 0.08838834764831845f * 1.4426950408889634f;

    conv_w<<<dim3(256, 4), 256, 0, stream>>>(wq, wk, wv, wp, Wb);
    gn_stats<<<128, 256, 0, stream>>>(x, stats);
    gn_apply<<<dim3(16, 32, 4), 256, 0, stream>>>(x, gnw, gnb, stats, XT);

    // Q and K projections fused into one dispatch: z=0 -> Q (bias bq, *qscale), z=1 -> K packed
    gemm_nt<3><<<dim3(128, 4, 2), 256, 0, stream>>>(XT, 0, Wb, 262144, bq, qscale, bk, 0,
                                                    Qb, (long long)NE, 512);
    // V projection -> packed Vp layout
    gemm_nt<2><<<dim3(4, 32, 4), 256, 0, stream>>>(Wb + 2 * 262144, 0, XT, (long long)HW * 512, bv, 1.f,
                                                   nullptr, 0, Vt, 0, HW);

    unsigned short* Ob = XT;   // XT dead after QKV; reuse for attention output (b,s,c)
    attn_kern<<<dim3(256), dim3(512), 0, stream>>>(Qb, Kb, Vt, Ob);

    // out[b,o,s] = sum_c wp[o,c] * Ob[b,s,c] + bp[o] + x[b,o,s]
    gemm_nt<1><<<dim3(4, 32, 4), 256, 0, stream>>>(Wb + 3 * 262144, 0, Ob, (long long)HW * 512, bp, 1.f,
                                                   x, (long long)CCH * HW, out, (long long)CCH * HW, HW);
}